// Round 7
// baseline (390.534 us; speedup 1.0000x reference)
//
#include <hip/hip_runtime.h>
#include <stdint.h>

// ---------------------------------------------------------------------------
// GAT bot detector, 2-layer, N=50000 E=800000 IN=256 HID=128 HEADS=4.
// Round 16: persistent grid-stride waves for agg1/agg2 (r15=376.3us best).
// agg1 pinned at VALU 52/HBM 52/Occ 42 with 12500 tiny blocks (~4 dsts each)
// -> block churn caps resident waves at ~3.4/SIMD, gather latency unhidden.
// Now 2048 blocks (8192 waves), each wave strides over ~6 dsts; inner loops
// unchanged (no __syncthreads in agg kernels -> per-wave looping race-free).
// Everything else unchanged from r15.
// ---------------------------------------------------------------------------

typedef _Float16 f16;
typedef f16 f16x8 __attribute__((ext_vector_type(8)));
typedef f16 f16x4 __attribute__((ext_vector_type(4)));
typedef f16 f16x2 __attribute__((ext_vector_type(2)));
typedef float f32x4 __attribute__((ext_vector_type(4)));

#if defined(__has_builtin)
#if __has_builtin(__builtin_amdgcn_fdot2)
#define HAS_FDOT2 1
#endif
#endif
#ifndef HAS_FDOT2
#define HAS_FDOT2 0
#endif

__device__ __forceinline__ float dot2f(f16x2 a, f16x2 b, float c) {
#if HAS_FDOT2
  return __builtin_amdgcn_fdot2(a, b, c, false);
#else
  return fmaf((float)a[0], (float)b[0], fmaf((float)a[1], (float)b[1], c));
#endif
}

// i64-layout ballot, per-block (wave 0).
__device__ __forceinline__ int block_i64_flag(const int* __restrict__ ei) {
  __shared__ int sflag;
  if (threadIdx.x < 64) {
    int nz = 0;
#pragma unroll
    for (int w = 0; w < 4; ++w) nz |= ei[2 * (threadIdx.x * 4 + w) + 1];
    unsigned long long b = __ballot(nz != 0);
    if (threadIdx.x == 0) sflag = (b == 0ull) ? 1 : 0;
  }
  __syncthreads();
  return sflag;
}

// ---------------- prep1: attw (blocks 0..3) | cvtw (4..195) | hist ---------
__global__ __launch_bounds__(256) void prep1_kernel(
    const float* __restrict__ W1, const float* __restrict__ s1,
    const float* __restrict__ d1, float* __restrict__ attWT,
    f16* __restrict__ B1f, const float* __restrict__ W2, f16* __restrict__ B2f,
    const int* __restrict__ ei, int E, int N, int* __restrict__ deg) {
  const int b = blockIdx.x;
  const int tid = threadIdx.x;
  if (b < 4) {  // ---- attw ----
    const int h = b, c = tid;
    float ps = 0.f, pd = 0.f;
    for (int k = 0; k < 128; ++k) {
      float w = W1[(size_t)(h * 128 + k) * 256 + c];
      ps = fmaf(w, s1[h * 128 + k], ps);
      pd = fmaf(w, d1[h * 128 + k], pd);
    }
    attWT[(h * 2 + 0) * 256 + c] = ps;
    attWT[(h * 2 + 1) * 256 + c] = pd;
    return;
  }
  if (b < 196) {  // ---- cvtw ----
    int idx = (b - 4) * 256 + tid;
    const float* src;
    f16* dst;
    int j;
    if (idx < 32768) { src = W1; dst = B1f; j = idx; }
    else { src = W2; dst = B2f; j = idx - 32768; }
    float4 v = *(const float4*)&src[(size_t)j * 4];
    f16x4 o = {(f16)v.x, (f16)v.y, (f16)v.z, (f16)v.w};
    *(f16x4*)&dst[(size_t)j * 4] = o;
    return;
  }
  // ---- hist ----
  const int flag = block_i64_flag(ei);
  int idx = (b - 196) * 256 + tid;
  int EA = E + N;
  if (idx >= EA) return;
  int dst;
  if (idx < E) {
    dst = flag ? ei[2 * ((size_t)E + idx)] : ei[(size_t)E + idx];
  } else {
    dst = idx - E;  // self loop
  }
  if ((unsigned)dst >= (unsigned)N) return;
  atomicAdd(&deg[dst], 1);
}

// ---------------- prep2: cvtx (blocks 0..CB-1) | scan1 (CB..) --------------
__global__ __launch_bounds__(256) void prep2_kernel(
    const float* __restrict__ x, const float* __restrict__ attWT,
    f16* __restrict__ xf, float* __restrict__ aS, float* __restrict__ aD,
    int n, int CB,
    const int* __restrict__ deg, int* __restrict__ tmp, int* __restrict__ bsum) {
  __shared__ int sd[256];
  const int t = threadIdx.x;
  if ((int)blockIdx.x >= CB) {  // ---- scan1 ----
    const int sb = blockIdx.x - CB;
    const int i = sb * 256 + t;
    int v = (i < n) ? deg[i] : 0;
    sd[t] = v;
    __syncthreads();
    for (int off = 1; off < 256; off <<= 1) {
      int u = (t >= off) ? sd[t - off] : 0;
      __syncthreads();
      sd[t] += u;
      __syncthreads();
    }
    if (i < n) tmp[i] = sd[t];
    if (t == 255) bsum[sb] = sd[255];
    return;
  }
  // ---- cvtx ----
  const int wv = t >> 6, lane = t & 63;
  float4 wr[8];
#pragma unroll
  for (int j = 0; j < 8; ++j) wr[j] = *(const float4*)&attWT[j * 256 + lane * 4];
  const int row0 = (blockIdx.x * 4 + wv) * 4;
#pragma unroll
  for (int r = 0; r < 4; ++r) {
    const int row = row0 + r;
    if (row >= n) return;
    const float4 v = *(const float4*)&x[(size_t)row * 256 + lane * 4];
    f16x4 o = {(f16)v.x, (f16)v.y, (f16)v.z, (f16)v.w};
    *(f16x4*)&xf[(size_t)row * 256 + lane * 4] = o;
    float p[8];
#pragma unroll
    for (int j = 0; j < 8; ++j)
      p[j] = v.x * wr[j].x + v.y * wr[j].y + v.z * wr[j].z + v.w * wr[j].w;
#pragma unroll
    for (int off = 32; off; off >>= 1)
#pragma unroll
      for (int j = 0; j < 8; ++j) p[j] += __shfl_xor(p[j], off);
    if (lane == 0) {
#pragma unroll
      for (int h = 0; h < 4; ++h) {
        aS[(size_t)row * 4 + h] = p[h * 2];
        aD[(size_t)row * 4 + h] = p[h * 2 + 1];
      }
    }
  }
}

// scan3 with fused block-offset reduction.
__global__ __launch_bounds__(256) void scan3_kernel(const int* __restrict__ deg,
                                                    const int* __restrict__ tmp,
                                                    const int* __restrict__ bsum,
                                                    int* __restrict__ row_ptr,
                                                    int* __restrict__ cursor, int n, int nb) {
  __shared__ int wsum[4];
  int v = 0;
  for (int t = threadIdx.x; t < nb; t += 256)
    if (t < (int)blockIdx.x) v += bsum[t];
#pragma unroll
  for (int off = 32; off; off >>= 1) v += __shfl_xor(v, off);
  if ((threadIdx.x & 63) == 0) wsum[threadIdx.x >> 6] = v;
  __syncthreads();
  const int boffb = wsum[0] + wsum[1] + wsum[2] + wsum[3];
  int i = blockIdx.x * 256 + threadIdx.x;
  if (i >= n) return;
  int g = tmp[i] + boffb;
  row_ptr[i + 1] = g;
  cursor[i] = g - deg[i];
  if (i == 0) row_ptr[0] = 0;
}

// scatter + fused alpha1: cse[pos] = {src, 0, alpha4(f16x4)}.
__global__ __launch_bounds__(256) void scatter_kernel(
    const int* __restrict__ ei, int E, int N,
    const float* __restrict__ aS, const float* __restrict__ aD,
    int* __restrict__ cursor, int4* __restrict__ cse) {
  const int flag = block_i64_flag(ei);
  int idx = blockIdx.x * blockDim.x + threadIdx.x;
  int EA = E + N;
  if (idx >= EA) return;
  int src, dst;
  if (idx < E) {
    if (flag) { src = ei[2 * (size_t)idx]; dst = ei[2 * ((size_t)E + idx)]; }
    else      { src = ei[(size_t)idx];     dst = ei[(size_t)E + idx]; }
  } else {
    src = dst = idx - E;
  }
  if ((unsigned)dst >= (unsigned)N || (unsigned)src >= (unsigned)N) return;
  const float4 s4 = *(const float4*)&aS[(size_t)src * 4];
  const float4 d4 = *(const float4*)&aD[(size_t)dst * 4];
  float x0 = s4.x + d4.x; x0 = (x0 > 0.f) ? x0 : 0.2f * x0;
  float x1 = s4.y + d4.y; x1 = (x1 > 0.f) ? x1 : 0.2f * x1;
  float x2 = s4.z + d4.z; x2 = (x2 > 0.f) ? x2 : 0.2f * x2;
  float x3 = s4.w + d4.w; x3 = (x3 > 0.f) ? x3 : 0.2f * x3;
  f16x4 a = {(f16)__expf(x0), (f16)__expf(x1), (f16)__expf(x2), (f16)__expf(x3)};
  const int2 ab = *(const int2*)&a;
  int pos = atomicAdd(&cursor[dst], 1);
  int4 w;
  w.x = src; w.y = 0; w.z = ab.x; w.w = ab.y;
  cse[pos] = w;
}

// ------------------- layer-1 x-space aggregation (per dst) -----------------
// Persistent grid-stride waves: each wave loops dsts with stride gridDim*4.
// Inner body identical to r15 (single 16B cse staging, dot2 pairs).
__global__ __launch_bounds__(256) void agg1_kernel(
    const int* __restrict__ row_ptr, const int4* __restrict__ cse,
    const f16* __restrict__ xf, f16* __restrict__ aggX, int n) {
  __shared__ __align__(16) int4 lent[4][64];
  const int wv = threadIdx.x >> 6, lane = threadIdx.x & 63;
  const int stride = gridDim.x * 4;
  const f16* __restrict__ xcol = xf + lane * 4;

  for (int dst = blockIdx.x * 4 + wv; dst < n; dst += stride) {
    const int beg = row_ptr[dst], end = row_ptr[dst + 1];
    f32x4 den4 = {0.f, 0.f, 0.f, 0.f};
    float acc[16];
#pragma unroll
    for (int q = 0; q < 16; ++q) acc[q] = 0.f;

    for (int base = beg; base < end; base += 64) {
      int i = base + lane;
      int4 w = make_int4(0, 0, 0, 0);  // alpha bits 0 -> +0.0h
      if (i < end) w = cse[i];
      const f16x2 dz = *(const f16x2*)&w.z;
      const f16x2 dw = *(const f16x2*)&w.w;
      den4[0] += (float)dz[0]; den4[1] += (float)dz[1];
      den4[2] += (float)dw[0]; den4[3] += (float)dw[1];
      lent[wv][lane] = w;
      asm volatile("s_waitcnt lgkmcnt(0)" ::: "memory");
      const int m = min(64, end - base);
      const int np = (m + 1) >> 1;   // pairs (odd tail pair has alpha=0 slot)
      const int fullp = np & ~3;     // 4-pair batches
      int p = 0;
      for (; p < fullp; p += 4) {
        int4 e0[4], e1[4];
        f16x4 v[8];
#pragma unroll
        for (int k = 0; k < 4; ++k) {
          e0[k] = lent[wv][2 * (p + k)];
          e1[k] = lent[wv][2 * (p + k) + 1];
        }
#pragma unroll
        for (int k = 0; k < 4; ++k) {
          v[2 * k]     = *(const f16x4*)&xcol[(size_t)e0[k].x * 256];
          v[2 * k + 1] = *(const f16x4*)&xcol[(size_t)e1[k].x * 256];
        }
#pragma unroll
        for (int k = 0; k < 4; ++k) {
          const f16x2 q00 = *(const f16x2*)&e0[k].z, q01 = *(const f16x2*)&e0[k].w;
          const f16x2 q10 = *(const f16x2*)&e1[k].z, q11 = *(const f16x2*)&e1[k].w;
          const f16x2 b0 = {q00[0], q10[0]}, b1 = {q00[1], q10[1]},
                      b2 = {q01[0], q11[0]}, b3 = {q01[1], q11[1]};
#pragma unroll
          for (int c = 0; c < 4; ++c) {
            const f16x2 xp = {v[2 * k][c], v[2 * k + 1][c]};
            acc[c]      = dot2f(xp, b0, acc[c]);
            acc[4 + c]  = dot2f(xp, b1, acc[4 + c]);
            acc[8 + c]  = dot2f(xp, b2, acc[8 + c]);
            acc[12 + c] = dot2f(xp, b3, acc[12 + c]);
          }
        }
      }
      for (; p < np; ++p) {  // wave-uniform tail, 0..3 pairs
        const int4 e0 = lent[wv][2 * p];
        const int4 e1 = lent[wv][2 * p + 1];
        const f16x4 v0 = *(const f16x4*)&xcol[(size_t)e0.x * 256];
        const f16x4 v1 = *(const f16x4*)&xcol[(size_t)e1.x * 256];
        const f16x2 q00 = *(const f16x2*)&e0.z, q01 = *(const f16x2*)&e0.w;
        const f16x2 q10 = *(const f16x2*)&e1.z, q11 = *(const f16x2*)&e1.w;
        const f16x2 b0 = {q00[0], q10[0]}, b1 = {q00[1], q10[1]},
                    b2 = {q01[0], q11[0]}, b3 = {q01[1], q11[1]};
#pragma unroll
        for (int c = 0; c < 4; ++c) {
          const f16x2 xp = {v0[c], v1[c]};
          acc[c]      = dot2f(xp, b0, acc[c]);
          acc[4 + c]  = dot2f(xp, b1, acc[4 + c]);
          acc[8 + c]  = dot2f(xp, b2, acc[8 + c]);
          acc[12 + c] = dot2f(xp, b3, acc[12 + c]);
        }
      }
    }
#pragma unroll
    for (int off = 32; off; off >>= 1) {
#pragma unroll
      for (int k = 0; k < 4; ++k) den4[k] += __shfl_xor(den4[k], off);
    }
    const float inv[4] = {1.f / den4[0], 1.f / den4[1], 1.f / den4[2], 1.f / den4[3]};
#pragma unroll
    for (int h = 0; h < 4; ++h) {
      f16x4 o = {(f16)(acc[h * 4 + 0] * inv[h]), (f16)(acc[h * 4 + 1] * inv[h]),
                 (f16)(acc[h * 4 + 2] * inv[h]), (f16)(acc[h * 4 + 3] * inv[h])};
      *(f16x4*)&aggX[(size_t)dst * 1024 + h * 256 + lane * 4] = o;
    }
  }
}

// ---------------- GEMM1 per head: A2 = elu(aggX_h @ W1_h^T + b1) -----------
__global__ __launch_bounds__(256) void gemm1_kernel(
    const f16* __restrict__ A, const f16* __restrict__ Bm,
    const float* __restrict__ bias, f16* __restrict__ C, int Nrows) {
  __shared__ f16 lA[128 * 32];
  __shared__ f16 lB[128 * 32];
  const int h = blockIdx.x;
  const int tid = threadIdx.x;
  const int w = tid >> 6, lane = tid & 63;
  const int wm = w >> 1, wn = w & 1;
  const int rowBase = blockIdx.y * 128;
  const int lrow = lane & 15, lk = lane >> 4;
  f32x4 acc[4][4];
#pragma unroll
  for (int i = 0; i < 4; ++i)
#pragma unroll
    for (int j = 0; j < 4; ++j) acc[i][j] = (f32x4){0.f, 0.f, 0.f, 0.f};

  for (int kv = 0; kv < 256; kv += 32) {
    f16x8 stA[2], stB[2];
#pragma unroll
    for (int s = 0; s < 2; ++s) {
      int q = s * 256 + tid;
      int r = q >> 2;
      int cs = (q & 3) ^ ((r >> 1) & 3);
      int row = rowBase + r;
      if (row >= Nrows) row = Nrows - 1;  // clamp: pad outputs unused
      stA[s] = *(const f16x8*)(A + (size_t)row * 1024 + h * 256 + kv + cs * 8);
    }
#pragma unroll
    for (int s = 0; s < 2; ++s) {
      int q = s * 256 + tid;
      int r = q >> 2;
      int cs = (q & 3) ^ ((r >> 1) & 3);
      stB[s] = *(const f16x8*)(Bm + (size_t)(h * 128 + r) * 256 + kv + cs * 8);
    }
#pragma unroll
    for (int s = 0; s < 2; ++s) *(f16x8*)&lA[(size_t)(s * 256 + tid) * 8] = stA[s];
#pragma unroll
    for (int s = 0; s < 2; ++s) *(f16x8*)&lB[(size_t)(s * 256 + tid) * 8] = stB[s];
    __syncthreads();
    f16x8 aF[4], bF[4];
#pragma unroll
    for (int i = 0; i < 4; ++i) {
      int ra = wm * 64 + i * 16 + lrow;
      aF[i] = *(const f16x8*)&lA[(ra * 4 + (lk ^ ((ra >> 1) & 3))) * 8];
      int rb = wn * 64 + i * 16 + lrow;
      bF[i] = *(const f16x8*)&lB[(rb * 4 + (lk ^ ((rb >> 1) & 3))) * 8];
    }
#pragma unroll
    for (int i = 0; i < 4; ++i)
#pragma unroll
      for (int j = 0; j < 4; ++j)
        acc[i][j] = __builtin_amdgcn_mfma_f32_16x16x32_f16(aF[i], bF[j], acc[i][j], 0, 0, 0);
    __syncthreads();
  }
  // epilogue: bias + ELU, store f16 (C/D layout: col=lane&15, row=(lane>>4)*4+reg)
  float bj[4];
#pragma unroll
  for (int j = 0; j < 4; ++j) bj[j] = bias[h * 128 + wn * 64 + j * 16 + lrow];
#pragma unroll
  for (int i = 0; i < 4; ++i) {
    int row0 = rowBase + wm * 64 + i * 16 + lk * 4;
#pragma unroll
    for (int j = 0; j < 4; ++j) {
      int col = h * 128 + wn * 64 + j * 16 + lrow;
#pragma unroll
      for (int rr = 0; rr < 4; ++rr) {
        float vv = acc[i][j][rr] + bj[j];
        vv = (vv > 0.f) ? vv : (__expf(vv) - 1.f);
        C[(size_t)(row0 + rr) * 512 + col] = (f16)vv;
      }
    }
  }
}

// ------------- GEMM2 (BM=64, TPB=256, wave-tile 32x64) + fused attn2 -------
__global__ __launch_bounds__(256) void gemm2_kernel(
    const f16* __restrict__ A, const f16* __restrict__ Bm, f16* __restrict__ C,
    const float* __restrict__ attS, const float* __restrict__ attD,
    float* __restrict__ aS, float* __restrict__ aD,
    int K, int Ncols, int Nrows) {
  __shared__ f16 lA[64 * 32];
  __shared__ f16 lB[128 * 32];
  const int tid = threadIdx.x;
  const int w = tid >> 6, lane = tid & 63;
  const int wm = w >> 1, wn = w & 1;
  const int rowBase = blockIdx.y * 64;
  const int lrow = lane & 15, lk = lane >> 4;
  f32x4 acc[2][4];
#pragma unroll
  for (int i = 0; i < 2; ++i)
#pragma unroll
    for (int j = 0; j < 4; ++j) acc[i][j] = (f32x4){0.f, 0.f, 0.f, 0.f};

  for (int kv = 0; kv < K; kv += 32) {
    f16x8 stA, stB[2];
    {
      int q = tid;
      int r = q >> 2;
      int cs = (q & 3) ^ ((r >> 1) & 3);
      stA = *(const f16x8*)(A + (size_t)(rowBase + r) * K + kv + cs * 8);
    }
#pragma unroll
    for (int s = 0; s < 2; ++s) {
      int q = s * 256 + tid;
      int r = q >> 2;
      int cs = (q & 3) ^ ((r >> 1) & 3);
      stB[s] = *(const f16x8*)(Bm + (size_t)r * K + kv + cs * 8);
    }
    *(f16x8*)&lA[(size_t)tid * 8] = stA;
#pragma unroll
    for (int s = 0; s < 2; ++s) *(f16x8*)&lB[(size_t)(s * 256 + tid) * 8] = stB[s];
    __syncthreads();
    f16x8 aF[2], bF[4];
#pragma unroll
    for (int i = 0; i < 2; ++i) {
      int ra = wm * 32 + i * 16 + lrow;
      aF[i] = *(const f16x8*)&lA[(ra * 4 + (lk ^ ((ra >> 1) & 3))) * 8];
    }
#pragma unroll
    for (int j = 0; j < 4; ++j) {
      int rb = wn * 64 + j * 16 + lrow;
      bF[j] = *(const f16x8*)&lB[(rb * 4 + (lk ^ ((rb >> 1) & 3))) * 8];
    }
#pragma unroll
    for (int i = 0; i < 2; ++i)
#pragma unroll
      for (int j = 0; j < 4; ++j)
        acc[i][j] = __builtin_amdgcn_mfma_f32_16x16x32_f16(aF[i], bF[j], acc[i][j], 0, 0, 0);
    __syncthreads();
  }
#pragma unroll
  for (int i = 0; i < 2; ++i) {
    int row0 = rowBase + wm * 32 + i * 16 + lk * 4;
#pragma unroll
    for (int j = 0; j < 4; ++j) {
      int col = wn * 64 + j * 16 + lrow;
#pragma unroll
      for (int rr = 0; rr < 4; ++rr)
        C[(size_t)(row0 + rr) * Ncols + col] = (f16)acc[i][j][rr];
    }
  }
  // Fused attn2 epilogue (H=1): rows split by wm, cols by wn.
  float sv[4], dv[4];
#pragma unroll
  for (int j = 0; j < 4; ++j) {
    int cl = wn * 64 + j * 16 + lrow;
    sv[j] = attS[cl];
    dv[j] = attD[cl];
  }
  __shared__ float sred[2][2][32][2];
#pragma unroll
  for (int i = 0; i < 2; ++i) {
#pragma unroll
    for (int rr = 0; rr < 4; ++rr) {
      float ps = 0.f, pd = 0.f;
#pragma unroll
      for (int j = 0; j < 4; ++j) {
        ps = fmaf(acc[i][j][rr], sv[j], ps);
        pd = fmaf(acc[i][j][rr], dv[j], pd);
      }
#pragma unroll
      for (int off = 1; off < 16; off <<= 1) {
        ps += __shfl_xor(ps, off);
        pd += __shfl_xor(pd, off);
      }
      if (lrow == 0) {
        int rloc = i * 16 + lk * 4 + rr;
        sred[wm][wn][rloc][0] = ps;
        sred[wm][wn][rloc][1] = pd;
      }
    }
  }
  __syncthreads();
  if (tid < 64) {
    int row = rowBase + tid;
    if (row < Nrows) {
      int m = tid >> 5, rl = tid & 31;
      aS[row] = sred[m][0][rl][0] + sred[m][1][rl][0];
      aD[row] = sred[m][0][rl][1] + sred[m][1][rl][1];
    }
  }
}

// ------------- layer-2 aggregation + ELU + fused classifier ----------------
// Persistent grid-stride waves (same rationale as agg1).
__global__ __launch_bounds__(256) void agg2_kernel(
    const int* __restrict__ row_ptr, const int4* __restrict__ cse,
    const float* __restrict__ aS, const float* __restrict__ aD,
    const f16* __restrict__ xw2, const float* __restrict__ b2,
    const float* __restrict__ Wc, const float* __restrict__ bc,
    float* __restrict__ out, int n) {
  __shared__ __align__(16) float2 led[4][64];
  const int wv = threadIdx.x >> 6, lane = threadIdx.x & 63;
  const int stride = gridDim.x * 4;
  const int half = lane >> 5, lc = lane & 31;
  const f16* __restrict__ xrow = xw2 + lc * 4;
  const int c = lc * 4;
  const float4 bb = *(const float4*)&b2[c];
  const float4 w0 = *(const float4*)&Wc[c];
  const float4 w1 = *(const float4*)&Wc[128 + c];
  const float bv[4] = {bb.x, bb.y, bb.z, bb.w};
  const float w0v[4] = {w0.x, w0.y, w0.z, w0.w};
  const float w1v[4] = {w1.x, w1.y, w1.z, w1.w};

  for (int dst = blockIdx.x * 4 + wv; dst < n; dst += stride) {
    const int beg = row_ptr[dst], end = row_ptr[dst + 1];
    const float ad = aD[dst];
    float den = 0.f;
    float acc[4] = {0.f, 0.f, 0.f, 0.f};

    for (int base = beg; base < end; base += 64) {
      int i = base + lane;
      float2 pa = make_float2(__int_as_float(0), 0.f);
      if (i < end) {
        int s = cse[i].x;
        float x = aS[s] + ad;
        x = (x > 0.f) ? x : 0.2f * x;
        pa = make_float2(__int_as_float(s), __expf(x));
      }
      den += pa.y;
      led[wv][lane] = pa;
      asm volatile("s_waitcnt lgkmcnt(0)" ::: "memory");
      const int m = min(64, end - base);
      const int np2 = (m + 1) >> 1;
      int p = 0;
      for (; p < (np2 & ~7); p += 8) {
        int sj[8];
        float aj[8];
        f16x4 v[8];
#pragma unroll
        for (int k = 0; k < 8; ++k) {
          float2 q = led[wv][(p + k) * 2 + half];
          sj[k] = __float_as_int(q.x);
          aj[k] = q.y;
        }
#pragma unroll
        for (int k = 0; k < 8; ++k) v[k] = *(const f16x4*)&xrow[(size_t)sj[k] * 128];
#pragma unroll
        for (int k = 0; k < 8; ++k) {
          acc[0] = fmaf(aj[k], (float)v[k][0], acc[0]);
          acc[1] = fmaf(aj[k], (float)v[k][1], acc[1]);
          acc[2] = fmaf(aj[k], (float)v[k][2], acc[2]);
          acc[3] = fmaf(aj[k], (float)v[k][3], acc[3]);
        }
      }
      for (; p < np2; ++p) {
        const float2 q = led[wv][p * 2 + half];
        const int s = __float_as_int(q.x);
        const float a = q.y;
        const f16x4 vv = *(const f16x4*)&xrow[(size_t)s * 128];
        acc[0] = fmaf(a, (float)vv[0], acc[0]);
        acc[1] = fmaf(a, (float)vv[1], acc[1]);
        acc[2] = fmaf(a, (float)vv[2], acc[2]);
        acc[3] = fmaf(a, (float)vv[3], acc[3]);
      }
    }
#pragma unroll
    for (int off = 32; off; off >>= 1) den += __shfl_xor(den, off);
    const float inv = 1.f / den;
#pragma unroll
    for (int k = 0; k < 4; ++k) acc[k] += __shfl_xor(acc[k], 32);
    float l0 = 0.f, l1 = 0.f;
#pragma unroll
    for (int k = 0; k < 4; ++k) {
      float vv = acc[k] * inv + bv[k];
      vv = (vv > 0.f) ? vv : (__expf(vv) - 1.f);
      l0 = fmaf(vv, w0v[k], l0);
      l1 = fmaf(vv, w1v[k], l1);
    }
#pragma unroll
    for (int off = 16; off; off >>= 1) {
      l0 += __shfl_xor(l0, off);
      l1 += __shfl_xor(l1, off);
    }
    if (lane == 0) {
      out[dst * 2] = l0 + bc[0];
      out[dst * 2 + 1] = l1 + bc[1];
    }
  }
}

// ---------------------------------------------------------------------------

extern "C" void kernel_launch(void* const* d_in, const int* in_sizes, int n_in,
                              void* d_out, int out_size, void* d_ws, size_t ws_size,
                              hipStream_t stream) {
  const float* x     = (const float*)d_in[0];
  const int*   ei    = (const int*)d_in[1];
  const float* W1    = (const float*)d_in[2];
  const float* att1s = (const float*)d_in[3];
  const float* att1d = (const float*)d_in[4];
  const float* b1    = (const float*)d_in[5];
  const float* W2    = (const float*)d_in[6];
  const float* att2s = (const float*)d_in[7];
  const float* att2d = (const float*)d_in[8];
  const float* b2    = (const float*)d_in[9];
  const float* Wc    = (const float*)d_in[10];
  const float* bc    = (const float*)d_in[11];
  float* out = (float*)d_out;

  const int N = in_sizes[0] / 256;
  const int E = in_sizes[1] / 2;
  const int EA = E + N;
  const int Mpad = (N + 127) & ~127;
  const int NB = (N + 255) / 256;
  const int EB = (EA + 255) / 256;
  const int CB = (N + 15) / 16;
  const int DB = (N + 3) / 4;
  const int AB = DB < 2048 ? DB : 2048;  // persistent-wave grid for agg1/agg2

  char* base = (char*)d_ws;
  size_t off = 0;
  auto alloc = [&](size_t bytes) -> char* {
    char* p = base + off;
    off = (off + bytes + 255) & ~(size_t)255;
    return p;
  };
  f16* aggX = (f16*)alloc((size_t)Mpad * 1024 * sizeof(f16));  // x-space agg (4 heads)
  f16* xf   = (f16*)alloc((size_t)Mpad * 256 * sizeof(f16));   // x in f16
  f16* B1f  = (f16*)alloc((size_t)512 * 256 * sizeof(f16));    // W1 f16
  f16* A2   = (f16*)alloc((size_t)Mpad * 512 * sizeof(f16));   // h = elu(layer1)
  f16* B2f  = (f16*)alloc((size_t)128 * 512 * sizeof(f16));    // W2 f16
  f16* xw2h = (f16*)alloc((size_t)Mpad * 128 * sizeof(f16));   // layer2 pre-agg
  float* attWT = (float*)alloc((size_t)8 * 256 * sizeof(float));
  float* aS1 = (float*)alloc((size_t)N * 4 * sizeof(float));
  float* aD1 = (float*)alloc((size_t)N * 4 * sizeof(float));
  float* aS2 = (float*)alloc((size_t)N * sizeof(float));
  float* aD2 = (float*)alloc((size_t)N * sizeof(float));
  int* deg     = (int*)alloc((size_t)N * sizeof(int));
  int* row_ptr = (int*)alloc((size_t)(N + 1) * sizeof(int));
  int* cursor  = (int*)alloc((size_t)N * sizeof(int));
  int4* cse    = (int4*)alloc((size_t)EA * sizeof(int4));  // {src,0,alpha4 f16x4}
  int* tmp     = (int*)alloc((size_t)N * sizeof(int));
  int* bsum    = (int*)alloc((size_t)NB * sizeof(int));
  (void)n_in; (void)out_size; (void)ws_size;

  hipMemsetAsync(deg, 0, (size_t)N * sizeof(int), stream);
  if (Mpad > N)  // zero A2 pad rows so GEMM2 pad outputs stay finite
    hipMemsetAsync(A2 + (size_t)N * 512, 0, (size_t)(Mpad - N) * 512 * sizeof(f16), stream);

  // prep1: attw (4) | cvtw (192) | hist (EB)   -- attw latency hidden
  prep1_kernel<<<196 + EB, 256, 0, stream>>>(W1, att1s, att1d, attWT,
                                             B1f, W2, B2f, ei, E, N, deg);
  // prep2: cvtx (CB) | scan1 (NB)
  prep2_kernel<<<CB + NB, 256, 0, stream>>>(x, attWT, xf, aS1, aD1, N, CB,
                                            deg, tmp, bsum);
  scan3_kernel<<<NB, 256, 0, stream>>>(deg, tmp, bsum, row_ptr, cursor, N, NB);
  scatter_kernel<<<EB, 256, 0, stream>>>(ei, E, N, aS1, aD1, cursor, cse);

  agg1_kernel<<<AB, 256, 0, stream>>>(row_ptr, cse, xf, aggX, N);

  dim3 g1(4, Mpad / 128);
  gemm1_kernel<<<g1, 256, 0, stream>>>(aggX, B1f, b1, A2, N);

  dim3 g2(1, Mpad / 64);
  gemm2_kernel<<<g2, 256, 0, stream>>>(A2, B2f, xw2h, att2s, att2d, aS2, aD2, 512, 128, N);

  agg2_kernel<<<AB, 256, 0, stream>>>(row_ptr, cse, aS2, aD2, xw2h, b2, Wc, bc, out, N);
}

// Round 8
// 382.859 us; speedup vs baseline: 1.0200x; 1.0200x over previous
//
#include <hip/hip_runtime.h>
#include <stdint.h>

// ---------------------------------------------------------------------------
// GAT bot detector, 2-layer, N=50000 E=800000 IN=256 HID=128 HEADS=4.
// Round 17: revert r16's persistent grid-stride (regressed 376->390: static
// assignment lost dynamic load balance + cse locality; occ 42->38). Back to
// r15 structure (best, 376.3) with ONE minimal change: 2 consecutive dsts
// per wave (6250 blocks, still dynamically scheduled) -- halves block churn,
// keeps contiguous-cse locality (dst pair shares L2 lines) and HW balancing.
// Everything else byte-identical to r15.
// ---------------------------------------------------------------------------

typedef _Float16 f16;
typedef f16 f16x8 __attribute__((ext_vector_type(8)));
typedef f16 f16x4 __attribute__((ext_vector_type(4)));
typedef f16 f16x2 __attribute__((ext_vector_type(2)));
typedef float f32x4 __attribute__((ext_vector_type(4)));

#if defined(__has_builtin)
#if __has_builtin(__builtin_amdgcn_fdot2)
#define HAS_FDOT2 1
#endif
#endif
#ifndef HAS_FDOT2
#define HAS_FDOT2 0
#endif

__device__ __forceinline__ float dot2f(f16x2 a, f16x2 b, float c) {
#if HAS_FDOT2
  return __builtin_amdgcn_fdot2(a, b, c, false);
#else
  return fmaf((float)a[0], (float)b[0], fmaf((float)a[1], (float)b[1], c));
#endif
}

// i64-layout ballot, per-block (wave 0).
__device__ __forceinline__ int block_i64_flag(const int* __restrict__ ei) {
  __shared__ int sflag;
  if (threadIdx.x < 64) {
    int nz = 0;
#pragma unroll
    for (int w = 0; w < 4; ++w) nz |= ei[2 * (threadIdx.x * 4 + w) + 1];
    unsigned long long b = __ballot(nz != 0);
    if (threadIdx.x == 0) sflag = (b == 0ull) ? 1 : 0;
  }
  __syncthreads();
  return sflag;
}

// ---------------- prep1: attw (blocks 0..3) | cvtw (4..195) | hist ---------
__global__ __launch_bounds__(256) void prep1_kernel(
    const float* __restrict__ W1, const float* __restrict__ s1,
    const float* __restrict__ d1, float* __restrict__ attWT,
    f16* __restrict__ B1f, const float* __restrict__ W2, f16* __restrict__ B2f,
    const int* __restrict__ ei, int E, int N, int* __restrict__ deg) {
  const int b = blockIdx.x;
  const int tid = threadIdx.x;
  if (b < 4) {  // ---- attw ----
    const int h = b, c = tid;
    float ps = 0.f, pd = 0.f;
    for (int k = 0; k < 128; ++k) {
      float w = W1[(size_t)(h * 128 + k) * 256 + c];
      ps = fmaf(w, s1[h * 128 + k], ps);
      pd = fmaf(w, d1[h * 128 + k], pd);
    }
    attWT[(h * 2 + 0) * 256 + c] = ps;
    attWT[(h * 2 + 1) * 256 + c] = pd;
    return;
  }
  if (b < 196) {  // ---- cvtw ----
    int idx = (b - 4) * 256 + tid;
    const float* src;
    f16* dst;
    int j;
    if (idx < 32768) { src = W1; dst = B1f; j = idx; }
    else { src = W2; dst = B2f; j = idx - 32768; }
    float4 v = *(const float4*)&src[(size_t)j * 4];
    f16x4 o = {(f16)v.x, (f16)v.y, (f16)v.z, (f16)v.w};
    *(f16x4*)&dst[(size_t)j * 4] = o;
    return;
  }
  // ---- hist ----
  const int flag = block_i64_flag(ei);
  int idx = (b - 196) * 256 + tid;
  int EA = E + N;
  if (idx >= EA) return;
  int dst;
  if (idx < E) {
    dst = flag ? ei[2 * ((size_t)E + idx)] : ei[(size_t)E + idx];
  } else {
    dst = idx - E;  // self loop
  }
  if ((unsigned)dst >= (unsigned)N) return;
  atomicAdd(&deg[dst], 1);
}

// ---------------- prep2: cvtx (blocks 0..CB-1) | scan1 (CB..) --------------
__global__ __launch_bounds__(256) void prep2_kernel(
    const float* __restrict__ x, const float* __restrict__ attWT,
    f16* __restrict__ xf, float* __restrict__ aS, float* __restrict__ aD,
    int n, int CB,
    const int* __restrict__ deg, int* __restrict__ tmp, int* __restrict__ bsum) {
  __shared__ int sd[256];
  const int t = threadIdx.x;
  if ((int)blockIdx.x >= CB) {  // ---- scan1 ----
    const int sb = blockIdx.x - CB;
    const int i = sb * 256 + t;
    int v = (i < n) ? deg[i] : 0;
    sd[t] = v;
    __syncthreads();
    for (int off = 1; off < 256; off <<= 1) {
      int u = (t >= off) ? sd[t - off] : 0;
      __syncthreads();
      sd[t] += u;
      __syncthreads();
    }
    if (i < n) tmp[i] = sd[t];
    if (t == 255) bsum[sb] = sd[255];
    return;
  }
  // ---- cvtx ----
  const int wv = t >> 6, lane = t & 63;
  float4 wr[8];
#pragma unroll
  for (int j = 0; j < 8; ++j) wr[j] = *(const float4*)&attWT[j * 256 + lane * 4];
  const int row0 = (blockIdx.x * 4 + wv) * 4;
#pragma unroll
  for (int r = 0; r < 4; ++r) {
    const int row = row0 + r;
    if (row >= n) return;
    const float4 v = *(const float4*)&x[(size_t)row * 256 + lane * 4];
    f16x4 o = {(f16)v.x, (f16)v.y, (f16)v.z, (f16)v.w};
    *(f16x4*)&xf[(size_t)row * 256 + lane * 4] = o;
    float p[8];
#pragma unroll
    for (int j = 0; j < 8; ++j)
      p[j] = v.x * wr[j].x + v.y * wr[j].y + v.z * wr[j].z + v.w * wr[j].w;
#pragma unroll
    for (int off = 32; off; off >>= 1)
#pragma unroll
      for (int j = 0; j < 8; ++j) p[j] += __shfl_xor(p[j], off);
    if (lane == 0) {
#pragma unroll
      for (int h = 0; h < 4; ++h) {
        aS[(size_t)row * 4 + h] = p[h * 2];
        aD[(size_t)row * 4 + h] = p[h * 2 + 1];
      }
    }
  }
}

// scan3 with fused block-offset reduction.
__global__ __launch_bounds__(256) void scan3_kernel(const int* __restrict__ deg,
                                                    const int* __restrict__ tmp,
                                                    const int* __restrict__ bsum,
                                                    int* __restrict__ row_ptr,
                                                    int* __restrict__ cursor, int n, int nb) {
  __shared__ int wsum[4];
  int v = 0;
  for (int t = threadIdx.x; t < nb; t += 256)
    if (t < (int)blockIdx.x) v += bsum[t];
#pragma unroll
  for (int off = 32; off; off >>= 1) v += __shfl_xor(v, off);
  if ((threadIdx.x & 63) == 0) wsum[threadIdx.x >> 6] = v;
  __syncthreads();
  const int boffb = wsum[0] + wsum[1] + wsum[2] + wsum[3];
  int i = blockIdx.x * 256 + threadIdx.x;
  if (i >= n) return;
  int g = tmp[i] + boffb;
  row_ptr[i + 1] = g;
  cursor[i] = g - deg[i];
  if (i == 0) row_ptr[0] = 0;
}

// scatter + fused alpha1: cse[pos] = {src, 0, alpha4(f16x4)}.
__global__ __launch_bounds__(256) void scatter_kernel(
    const int* __restrict__ ei, int E, int N,
    const float* __restrict__ aS, const float* __restrict__ aD,
    int* __restrict__ cursor, int4* __restrict__ cse) {
  const int flag = block_i64_flag(ei);
  int idx = blockIdx.x * blockDim.x + threadIdx.x;
  int EA = E + N;
  if (idx >= EA) return;
  int src, dst;
  if (idx < E) {
    if (flag) { src = ei[2 * (size_t)idx]; dst = ei[2 * ((size_t)E + idx)]; }
    else      { src = ei[(size_t)idx];     dst = ei[(size_t)E + idx]; }
  } else {
    src = dst = idx - E;
  }
  if ((unsigned)dst >= (unsigned)N || (unsigned)src >= (unsigned)N) return;
  const float4 s4 = *(const float4*)&aS[(size_t)src * 4];
  const float4 d4 = *(const float4*)&aD[(size_t)dst * 4];
  float x0 = s4.x + d4.x; x0 = (x0 > 0.f) ? x0 : 0.2f * x0;
  float x1 = s4.y + d4.y; x1 = (x1 > 0.f) ? x1 : 0.2f * x1;
  float x2 = s4.z + d4.z; x2 = (x2 > 0.f) ? x2 : 0.2f * x2;
  float x3 = s4.w + d4.w; x3 = (x3 > 0.f) ? x3 : 0.2f * x3;
  f16x4 a = {(f16)__expf(x0), (f16)__expf(x1), (f16)__expf(x2), (f16)__expf(x3)};
  const int2 ab = *(const int2*)&a;
  int pos = atomicAdd(&cursor[dst], 1);
  int4 w;
  w.x = src; w.y = 0; w.z = ab.x; w.w = ab.y;
  cse[pos] = w;
}

// ------------------- layer-1 x-space aggregation (per dst) -----------------
// Dynamic blocks; each wave handles 2 CONSECUTIVE dsts (block = 8 dsts).
// Inner body identical to r15 (single 16B cse staging, dot2 pairs).
__global__ __launch_bounds__(256) void agg1_kernel(
    const int* __restrict__ row_ptr, const int4* __restrict__ cse,
    const f16* __restrict__ xf, f16* __restrict__ aggX, int n) {
  __shared__ __align__(16) int4 lent[4][64];
  const int wv = threadIdx.x >> 6, lane = threadIdx.x & 63;
  const int dst0 = blockIdx.x * 8 + wv * 2;
  const f16* __restrict__ xcol = xf + lane * 4;

#pragma unroll
  for (int d = 0; d < 2; ++d) {
    const int dst = dst0 + d;
    if (dst >= n) return;
    const int beg = row_ptr[dst], end = row_ptr[dst + 1];
    f32x4 den4 = {0.f, 0.f, 0.f, 0.f};
    float acc[16];
#pragma unroll
    for (int q = 0; q < 16; ++q) acc[q] = 0.f;

    for (int base = beg; base < end; base += 64) {
      int i = base + lane;
      int4 w = make_int4(0, 0, 0, 0);  // alpha bits 0 -> +0.0h
      if (i < end) w = cse[i];
      const f16x2 dz = *(const f16x2*)&w.z;
      const f16x2 dw = *(const f16x2*)&w.w;
      den4[0] += (float)dz[0]; den4[1] += (float)dz[1];
      den4[2] += (float)dw[0]; den4[3] += (float)dw[1];
      lent[wv][lane] = w;
      asm volatile("s_waitcnt lgkmcnt(0)" ::: "memory");
      const int m = min(64, end - base);
      const int np = (m + 1) >> 1;   // pairs (odd tail pair has alpha=0 slot)
      const int fullp = np & ~3;     // 4-pair batches
      int p = 0;
      for (; p < fullp; p += 4) {
        int4 e0[4], e1[4];
        f16x4 v[8];
#pragma unroll
        for (int k = 0; k < 4; ++k) {
          e0[k] = lent[wv][2 * (p + k)];
          e1[k] = lent[wv][2 * (p + k) + 1];
        }
#pragma unroll
        for (int k = 0; k < 4; ++k) {
          v[2 * k]     = *(const f16x4*)&xcol[(size_t)e0[k].x * 256];
          v[2 * k + 1] = *(const f16x4*)&xcol[(size_t)e1[k].x * 256];
        }
#pragma unroll
        for (int k = 0; k < 4; ++k) {
          const f16x2 q00 = *(const f16x2*)&e0[k].z, q01 = *(const f16x2*)&e0[k].w;
          const f16x2 q10 = *(const f16x2*)&e1[k].z, q11 = *(const f16x2*)&e1[k].w;
          const f16x2 b0 = {q00[0], q10[0]}, b1 = {q00[1], q10[1]},
                      b2 = {q01[0], q11[0]}, b3 = {q01[1], q11[1]};
#pragma unroll
          for (int c = 0; c < 4; ++c) {
            const f16x2 xp = {v[2 * k][c], v[2 * k + 1][c]};
            acc[c]      = dot2f(xp, b0, acc[c]);
            acc[4 + c]  = dot2f(xp, b1, acc[4 + c]);
            acc[8 + c]  = dot2f(xp, b2, acc[8 + c]);
            acc[12 + c] = dot2f(xp, b3, acc[12 + c]);
          }
        }
      }
      for (; p < np; ++p) {  // wave-uniform tail, 0..3 pairs
        const int4 e0 = lent[wv][2 * p];
        const int4 e1 = lent[wv][2 * p + 1];
        const f16x4 v0 = *(const f16x4*)&xcol[(size_t)e0.x * 256];
        const f16x4 v1 = *(const f16x4*)&xcol[(size_t)e1.x * 256];
        const f16x2 q00 = *(const f16x2*)&e0.z, q01 = *(const f16x2*)&e0.w;
        const f16x2 q10 = *(const f16x2*)&e1.z, q11 = *(const f16x2*)&e1.w;
        const f16x2 b0 = {q00[0], q10[0]}, b1 = {q00[1], q10[1]},
                    b2 = {q01[0], q11[0]}, b3 = {q01[1], q11[1]};
#pragma unroll
        for (int c = 0; c < 4; ++c) {
          const f16x2 xp = {v0[c], v1[c]};
          acc[c]      = dot2f(xp, b0, acc[c]);
          acc[4 + c]  = dot2f(xp, b1, acc[4 + c]);
          acc[8 + c]  = dot2f(xp, b2, acc[8 + c]);
          acc[12 + c] = dot2f(xp, b3, acc[12 + c]);
        }
      }
    }
#pragma unroll
    for (int off = 32; off; off >>= 1) {
#pragma unroll
      for (int k = 0; k < 4; ++k) den4[k] += __shfl_xor(den4[k], off);
    }
    const float inv[4] = {1.f / den4[0], 1.f / den4[1], 1.f / den4[2], 1.f / den4[3]};
#pragma unroll
    for (int h = 0; h < 4; ++h) {
      f16x4 o = {(f16)(acc[h * 4 + 0] * inv[h]), (f16)(acc[h * 4 + 1] * inv[h]),
                 (f16)(acc[h * 4 + 2] * inv[h]), (f16)(acc[h * 4 + 3] * inv[h])};
      *(f16x4*)&aggX[(size_t)dst * 1024 + h * 256 + lane * 4] = o;
    }
  }
}

// ---------------- GEMM1 per head: A2 = elu(aggX_h @ W1_h^T + b1) -----------
__global__ __launch_bounds__(256) void gemm1_kernel(
    const f16* __restrict__ A, const f16* __restrict__ Bm,
    const float* __restrict__ bias, f16* __restrict__ C, int Nrows) {
  __shared__ f16 lA[128 * 32];
  __shared__ f16 lB[128 * 32];
  const int h = blockIdx.x;
  const int tid = threadIdx.x;
  const int w = tid >> 6, lane = tid & 63;
  const int wm = w >> 1, wn = w & 1;
  const int rowBase = blockIdx.y * 128;
  const int lrow = lane & 15, lk = lane >> 4;
  f32x4 acc[4][4];
#pragma unroll
  for (int i = 0; i < 4; ++i)
#pragma unroll
    for (int j = 0; j < 4; ++j) acc[i][j] = (f32x4){0.f, 0.f, 0.f, 0.f};

  for (int kv = 0; kv < 256; kv += 32) {
    f16x8 stA[2], stB[2];
#pragma unroll
    for (int s = 0; s < 2; ++s) {
      int q = s * 256 + tid;
      int r = q >> 2;
      int cs = (q & 3) ^ ((r >> 1) & 3);
      int row = rowBase + r;
      if (row >= Nrows) row = Nrows - 1;  // clamp: pad outputs unused
      stA[s] = *(const f16x8*)(A + (size_t)row * 1024 + h * 256 + kv + cs * 8);
    }
#pragma unroll
    for (int s = 0; s < 2; ++s) {
      int q = s * 256 + tid;
      int r = q >> 2;
      int cs = (q & 3) ^ ((r >> 1) & 3);
      stB[s] = *(const f16x8*)(Bm + (size_t)(h * 128 + r) * 256 + kv + cs * 8);
    }
#pragma unroll
    for (int s = 0; s < 2; ++s) *(f16x8*)&lA[(size_t)(s * 256 + tid) * 8] = stA[s];
#pragma unroll
    for (int s = 0; s < 2; ++s) *(f16x8*)&lB[(size_t)(s * 256 + tid) * 8] = stB[s];
    __syncthreads();
    f16x8 aF[4], bF[4];
#pragma unroll
    for (int i = 0; i < 4; ++i) {
      int ra = wm * 64 + i * 16 + lrow;
      aF[i] = *(const f16x8*)&lA[(ra * 4 + (lk ^ ((ra >> 1) & 3))) * 8];
      int rb = wn * 64 + i * 16 + lrow;
      bF[i] = *(const f16x8*)&lB[(rb * 4 + (lk ^ ((rb >> 1) & 3))) * 8];
    }
#pragma unroll
    for (int i = 0; i < 4; ++i)
#pragma unroll
      for (int j = 0; j < 4; ++j)
        acc[i][j] = __builtin_amdgcn_mfma_f32_16x16x32_f16(aF[i], bF[j], acc[i][j], 0, 0, 0);
    __syncthreads();
  }
  // epilogue: bias + ELU, store f16 (C/D layout: col=lane&15, row=(lane>>4)*4+reg)
  float bj[4];
#pragma unroll
  for (int j = 0; j < 4; ++j) bj[j] = bias[h * 128 + wn * 64 + j * 16 + lrow];
#pragma unroll
  for (int i = 0; i < 4; ++i) {
    int row0 = rowBase + wm * 64 + i * 16 + lk * 4;
#pragma unroll
    for (int j = 0; j < 4; ++j) {
      int col = h * 128 + wn * 64 + j * 16 + lrow;
#pragma unroll
      for (int rr = 0; rr < 4; ++rr) {
        float vv = acc[i][j][rr] + bj[j];
        vv = (vv > 0.f) ? vv : (__expf(vv) - 1.f);
        C[(size_t)(row0 + rr) * 512 + col] = (f16)vv;
      }
    }
  }
}

// ------------- GEMM2 (BM=64, TPB=256, wave-tile 32x64) + fused attn2 -------
__global__ __launch_bounds__(256) void gemm2_kernel(
    const f16* __restrict__ A, const f16* __restrict__ Bm, f16* __restrict__ C,
    const float* __restrict__ attS, const float* __restrict__ attD,
    float* __restrict__ aS, float* __restrict__ aD,
    int K, int Ncols, int Nrows) {
  __shared__ f16 lA[64 * 32];
  __shared__ f16 lB[128 * 32];
  const int tid = threadIdx.x;
  const int w = tid >> 6, lane = tid & 63;
  const int wm = w >> 1, wn = w & 1;
  const int rowBase = blockIdx.y * 64;
  const int lrow = lane & 15, lk = lane >> 4;
  f32x4 acc[2][4];
#pragma unroll
  for (int i = 0; i < 2; ++i)
#pragma unroll
    for (int j = 0; j < 4; ++j) acc[i][j] = (f32x4){0.f, 0.f, 0.f, 0.f};

  for (int kv = 0; kv < K; kv += 32) {
    f16x8 stA, stB[2];
    {
      int q = tid;
      int r = q >> 2;
      int cs = (q & 3) ^ ((r >> 1) & 3);
      stA = *(const f16x8*)(A + (size_t)(rowBase + r) * K + kv + cs * 8);
    }
#pragma unroll
    for (int s = 0; s < 2; ++s) {
      int q = s * 256 + tid;
      int r = q >> 2;
      int cs = (q & 3) ^ ((r >> 1) & 3);
      stB[s] = *(const f16x8*)(Bm + (size_t)r * K + kv + cs * 8);
    }
    *(f16x8*)&lA[(size_t)tid * 8] = stA;
#pragma unroll
    for (int s = 0; s < 2; ++s) *(f16x8*)&lB[(size_t)(s * 256 + tid) * 8] = stB[s];
    __syncthreads();
    f16x8 aF[2], bF[4];
#pragma unroll
    for (int i = 0; i < 2; ++i) {
      int ra = wm * 32 + i * 16 + lrow;
      aF[i] = *(const f16x8*)&lA[(ra * 4 + (lk ^ ((ra >> 1) & 3))) * 8];
    }
#pragma unroll
    for (int j = 0; j < 4; ++j) {
      int rb = wn * 64 + j * 16 + lrow;
      bF[j] = *(const f16x8*)&lB[(rb * 4 + (lk ^ ((rb >> 1) & 3))) * 8];
    }
#pragma unroll
    for (int i = 0; i < 2; ++i)
#pragma unroll
      for (int j = 0; j < 4; ++j)
        acc[i][j] = __builtin_amdgcn_mfma_f32_16x16x32_f16(aF[i], bF[j], acc[i][j], 0, 0, 0);
    __syncthreads();
  }
#pragma unroll
  for (int i = 0; i < 2; ++i) {
    int row0 = rowBase + wm * 32 + i * 16 + lk * 4;
#pragma unroll
    for (int j = 0; j < 4; ++j) {
      int col = wn * 64 + j * 16 + lrow;
#pragma unroll
      for (int rr = 0; rr < 4; ++rr)
        C[(size_t)(row0 + rr) * Ncols + col] = (f16)acc[i][j][rr];
    }
  }
  // Fused attn2 epilogue (H=1): rows split by wm, cols by wn.
  float sv[4], dv[4];
#pragma unroll
  for (int j = 0; j < 4; ++j) {
    int cl = wn * 64 + j * 16 + lrow;
    sv[j] = attS[cl];
    dv[j] = attD[cl];
  }
  __shared__ float sred[2][2][32][2];
#pragma unroll
  for (int i = 0; i < 2; ++i) {
#pragma unroll
    for (int rr = 0; rr < 4; ++rr) {
      float ps = 0.f, pd = 0.f;
#pragma unroll
      for (int j = 0; j < 4; ++j) {
        ps = fmaf(acc[i][j][rr], sv[j], ps);
        pd = fmaf(acc[i][j][rr], dv[j], pd);
      }
#pragma unroll
      for (int off = 1; off < 16; off <<= 1) {
        ps += __shfl_xor(ps, off);
        pd += __shfl_xor(pd, off);
      }
      if (lrow == 0) {
        int rloc = i * 16 + lk * 4 + rr;
        sred[wm][wn][rloc][0] = ps;
        sred[wm][wn][rloc][1] = pd;
      }
    }
  }
  __syncthreads();
  if (tid < 64) {
    int row = rowBase + tid;
    if (row < Nrows) {
      int m = tid >> 5, rl = tid & 31;
      aS[row] = sred[m][0][rl][0] + sred[m][1][rl][0];
      aD[row] = sred[m][0][rl][1] + sred[m][1][rl][1];
    }
  }
}

// ------------- layer-2 aggregation + ELU + fused classifier ----------------
// Dynamic blocks; 2 consecutive dsts per wave (same rationale as agg1).
__global__ __launch_bounds__(256) void agg2_kernel(
    const int* __restrict__ row_ptr, const int4* __restrict__ cse,
    const float* __restrict__ aS, const float* __restrict__ aD,
    const f16* __restrict__ xw2, const float* __restrict__ b2,
    const float* __restrict__ Wc, const float* __restrict__ bc,
    float* __restrict__ out, int n) {
  __shared__ __align__(16) float2 led[4][64];
  const int wv = threadIdx.x >> 6, lane = threadIdx.x & 63;
  const int dst0 = blockIdx.x * 8 + wv * 2;
  const int half = lane >> 5, lc = lane & 31;
  const f16* __restrict__ xrow = xw2 + lc * 4;
  const int c = lc * 4;
  const float4 bb = *(const float4*)&b2[c];
  const float4 w0 = *(const float4*)&Wc[c];
  const float4 w1 = *(const float4*)&Wc[128 + c];
  const float bv[4] = {bb.x, bb.y, bb.z, bb.w};
  const float w0v[4] = {w0.x, w0.y, w0.z, w0.w};
  const float w1v[4] = {w1.x, w1.y, w1.z, w1.w};

#pragma unroll
  for (int d = 0; d < 2; ++d) {
    const int dst = dst0 + d;
    if (dst >= n) return;
    const int beg = row_ptr[dst], end = row_ptr[dst + 1];
    const float ad = aD[dst];
    float den = 0.f;
    float acc[4] = {0.f, 0.f, 0.f, 0.f};

    for (int base = beg; base < end; base += 64) {
      int i = base + lane;
      float2 pa = make_float2(__int_as_float(0), 0.f);
      if (i < end) {
        int s = cse[i].x;
        float x = aS[s] + ad;
        x = (x > 0.f) ? x : 0.2f * x;
        pa = make_float2(__int_as_float(s), __expf(x));
      }
      den += pa.y;
      led[wv][lane] = pa;
      asm volatile("s_waitcnt lgkmcnt(0)" ::: "memory");
      const int m = min(64, end - base);
      const int np2 = (m + 1) >> 1;
      int p = 0;
      for (; p < (np2 & ~7); p += 8) {
        int sj[8];
        float aj[8];
        f16x4 v[8];
#pragma unroll
        for (int k = 0; k < 8; ++k) {
          float2 q = led[wv][(p + k) * 2 + half];
          sj[k] = __float_as_int(q.x);
          aj[k] = q.y;
        }
#pragma unroll
        for (int k = 0; k < 8; ++k) v[k] = *(const f16x4*)&xrow[(size_t)sj[k] * 128];
#pragma unroll
        for (int k = 0; k < 8; ++k) {
          acc[0] = fmaf(aj[k], (float)v[k][0], acc[0]);
          acc[1] = fmaf(aj[k], (float)v[k][1], acc[1]);
          acc[2] = fmaf(aj[k], (float)v[k][2], acc[2]);
          acc[3] = fmaf(aj[k], (float)v[k][3], acc[3]);
        }
      }
      for (; p < np2; ++p) {
        const float2 q = led[wv][p * 2 + half];
        const int s = __float_as_int(q.x);
        const float a = q.y;
        const f16x4 vv = *(const f16x4*)&xrow[(size_t)s * 128];
        acc[0] = fmaf(a, (float)vv[0], acc[0]);
        acc[1] = fmaf(a, (float)vv[1], acc[1]);
        acc[2] = fmaf(a, (float)vv[2], acc[2]);
        acc[3] = fmaf(a, (float)vv[3], acc[3]);
      }
    }
#pragma unroll
    for (int off = 32; off; off >>= 1) den += __shfl_xor(den, off);
    const float inv = 1.f / den;
#pragma unroll
    for (int k = 0; k < 4; ++k) acc[k] += __shfl_xor(acc[k], 32);
    float l0 = 0.f, l1 = 0.f;
#pragma unroll
    for (int k = 0; k < 4; ++k) {
      float vv = acc[k] * inv + bv[k];
      vv = (vv > 0.f) ? vv : (__expf(vv) - 1.f);
      l0 = fmaf(vv, w0v[k], l0);
      l1 = fmaf(vv, w1v[k], l1);
    }
#pragma unroll
    for (int off = 16; off; off >>= 1) {
      l0 += __shfl_xor(l0, off);
      l1 += __shfl_xor(l1, off);
    }
    if (lane == 0) {
      out[dst * 2] = l0 + bc[0];
      out[dst * 2 + 1] = l1 + bc[1];
    }
  }
}

// ---------------------------------------------------------------------------

extern "C" void kernel_launch(void* const* d_in, const int* in_sizes, int n_in,
                              void* d_out, int out_size, void* d_ws, size_t ws_size,
                              hipStream_t stream) {
  const float* x     = (const float*)d_in[0];
  const int*   ei    = (const int*)d_in[1];
  const float* W1    = (const float*)d_in[2];
  const float* att1s = (const float*)d_in[3];
  const float* att1d = (const float*)d_in[4];
  const float* b1    = (const float*)d_in[5];
  const float* W2    = (const float*)d_in[6];
  const float* att2s = (const float*)d_in[7];
  const float* att2d = (const float*)d_in[8];
  const float* b2    = (const float*)d_in[9];
  const float* Wc    = (const float*)d_in[10];
  const float* bc    = (const float*)d_in[11];
  float* out = (float*)d_out;

  const int N = in_sizes[0] / 256;
  const int E = in_sizes[1] / 2;
  const int EA = E + N;
  const int Mpad = (N + 127) & ~127;
  const int NB = (N + 255) / 256;
  const int EB = (EA + 255) / 256;
  const int CB = (N + 15) / 16;
  const int DB8 = (N + 7) / 8;  // 2 dsts/wave, 8 dsts/block

  char* base = (char*)d_ws;
  size_t off = 0;
  auto alloc = [&](size_t bytes) -> char* {
    char* p = base + off;
    off = (off + bytes + 255) & ~(size_t)255;
    return p;
  };
  f16* aggX = (f16*)alloc((size_t)Mpad * 1024 * sizeof(f16));  // x-space agg (4 heads)
  f16* xf   = (f16*)alloc((size_t)Mpad * 256 * sizeof(f16));   // x in f16
  f16* B1f  = (f16*)alloc((size_t)512 * 256 * sizeof(f16));    // W1 f16
  f16* A2   = (f16*)alloc((size_t)Mpad * 512 * sizeof(f16));   // h = elu(layer1)
  f16* B2f  = (f16*)alloc((size_t)128 * 512 * sizeof(f16));    // W2 f16
  f16* xw2h = (f16*)alloc((size_t)Mpad * 128 * sizeof(f16));   // layer2 pre-agg
  float* attWT = (float*)alloc((size_t)8 * 256 * sizeof(float));
  float* aS1 = (float*)alloc((size_t)N * 4 * sizeof(float));
  float* aD1 = (float*)alloc((size_t)N * 4 * sizeof(float));
  float* aS2 = (float*)alloc((size_t)N * sizeof(float));
  float* aD2 = (float*)alloc((size_t)N * sizeof(float));
  int* deg     = (int*)alloc((size_t)N * sizeof(int));
  int* row_ptr = (int*)alloc((size_t)(N + 1) * sizeof(int));
  int* cursor  = (int*)alloc((size_t)N * sizeof(int));
  int4* cse    = (int4*)alloc((size_t)EA * sizeof(int4));  // {src,0,alpha4 f16x4}
  int* tmp     = (int*)alloc((size_t)N * sizeof(int));
  int* bsum    = (int*)alloc((size_t)NB * sizeof(int));
  (void)n_in; (void)out_size; (void)ws_size;

  hipMemsetAsync(deg, 0, (size_t)N * sizeof(int), stream);
  if (Mpad > N)  // zero A2 pad rows so GEMM2 pad outputs stay finite
    hipMemsetAsync(A2 + (size_t)N * 512, 0, (size_t)(Mpad - N) * 512 * sizeof(f16), stream);

  // prep1: attw (4) | cvtw (192) | hist (EB)   -- attw latency hidden
  prep1_kernel<<<196 + EB, 256, 0, stream>>>(W1, att1s, att1d, attWT,
                                             B1f, W2, B2f, ei, E, N, deg);
  // prep2: cvtx (CB) | scan1 (NB)
  prep2_kernel<<<CB + NB, 256, 0, stream>>>(x, attWT, xf, aS1, aD1, N, CB,
                                            deg, tmp, bsum);
  scan3_kernel<<<NB, 256, 0, stream>>>(deg, tmp, bsum, row_ptr, cursor, N, NB);
  scatter_kernel<<<EB, 256, 0, stream>>>(ei, E, N, aS1, aD1, cursor, cse);

  agg1_kernel<<<DB8, 256, 0, stream>>>(row_ptr, cse, xf, aggX, N);

  dim3 g1(4, Mpad / 128);
  gemm1_kernel<<<g1, 256, 0, stream>>>(aggX, B1f, b1, A2, N);

  dim3 g2(1, Mpad / 64);
  gemm2_kernel<<<g2, 256, 0, stream>>>(A2, B2f, xw2h, att2s, att2d, aS2, aD2, 512, 128, N);

  agg2_kernel<<<DB8, 256, 0, stream>>>(row_ptr, cse, aS2, aD2, xw2h, b2, Wc, bc, out, N);
}

// Round 9
// 377.541 us; speedup vs baseline: 1.0344x; 1.0141x over previous
//
#include <hip/hip_runtime.h>
#include <stdint.h>

// ---------------------------------------------------------------------------
// GAT bot detector, 2-layer, N=50000 E=800000 IN=256 HID=128 HEADS=4.
// Round 18: r15 base (376.3us best; r16/r17 grid experiments both lost ->
// dynamic 1-dst-per-wave is right). One surgical change: agg1's inner loop
// moves wave-uniform edge records from LDS round-trip (2x ds_read_b128 +
// 4x v_perm per pair, 400K bank conflicts) to SGPRs via readlane; pair-alpha
// packing on SALU (co-issues); gathers get scalar-base addressing. LDS=0,
// lgkm waits gone, VALU stream ~pure dot2. agg2/others byte-identical r15.
// ---------------------------------------------------------------------------

typedef _Float16 f16;
typedef f16 f16x8 __attribute__((ext_vector_type(8)));
typedef f16 f16x4 __attribute__((ext_vector_type(4)));
typedef f16 f16x2 __attribute__((ext_vector_type(2)));
typedef float f32x4 __attribute__((ext_vector_type(4)));

#if defined(__has_builtin)
#if __has_builtin(__builtin_amdgcn_fdot2)
#define HAS_FDOT2 1
#endif
#endif
#ifndef HAS_FDOT2
#define HAS_FDOT2 0
#endif

__device__ __forceinline__ float dot2f(f16x2 a, f16x2 b, float c) {
#if HAS_FDOT2
  return __builtin_amdgcn_fdot2(a, b, c, false);
#else
  return fmaf((float)a[0], (float)b[0], fmaf((float)a[1], (float)b[1], c));
#endif
}

__device__ __forceinline__ f16x2 u2h(unsigned u) {
  union { unsigned u; f16x2 h; } c;
  c.u = u;
  return c.h;
}

// i64-layout ballot, per-block (wave 0).
__device__ __forceinline__ int block_i64_flag(const int* __restrict__ ei) {
  __shared__ int sflag;
  if (threadIdx.x < 64) {
    int nz = 0;
#pragma unroll
    for (int w = 0; w < 4; ++w) nz |= ei[2 * (threadIdx.x * 4 + w) + 1];
    unsigned long long b = __ballot(nz != 0);
    if (threadIdx.x == 0) sflag = (b == 0ull) ? 1 : 0;
  }
  __syncthreads();
  return sflag;
}

// ---------------- prep1: attw (blocks 0..3) | cvtw (4..195) | hist ---------
__global__ __launch_bounds__(256) void prep1_kernel(
    const float* __restrict__ W1, const float* __restrict__ s1,
    const float* __restrict__ d1, float* __restrict__ attWT,
    f16* __restrict__ B1f, const float* __restrict__ W2, f16* __restrict__ B2f,
    const int* __restrict__ ei, int E, int N, int* __restrict__ deg) {
  const int b = blockIdx.x;
  const int tid = threadIdx.x;
  if (b < 4) {  // ---- attw ----
    const int h = b, c = tid;
    float ps = 0.f, pd = 0.f;
    for (int k = 0; k < 128; ++k) {
      float w = W1[(size_t)(h * 128 + k) * 256 + c];
      ps = fmaf(w, s1[h * 128 + k], ps);
      pd = fmaf(w, d1[h * 128 + k], pd);
    }
    attWT[(h * 2 + 0) * 256 + c] = ps;
    attWT[(h * 2 + 1) * 256 + c] = pd;
    return;
  }
  if (b < 196) {  // ---- cvtw ----
    int idx = (b - 4) * 256 + tid;
    const float* src;
    f16* dst;
    int j;
    if (idx < 32768) { src = W1; dst = B1f; j = idx; }
    else { src = W2; dst = B2f; j = idx - 32768; }
    float4 v = *(const float4*)&src[(size_t)j * 4];
    f16x4 o = {(f16)v.x, (f16)v.y, (f16)v.z, (f16)v.w};
    *(f16x4*)&dst[(size_t)j * 4] = o;
    return;
  }
  // ---- hist ----
  const int flag = block_i64_flag(ei);
  int idx = (b - 196) * 256 + tid;
  int EA = E + N;
  if (idx >= EA) return;
  int dst;
  if (idx < E) {
    dst = flag ? ei[2 * ((size_t)E + idx)] : ei[(size_t)E + idx];
  } else {
    dst = idx - E;  // self loop
  }
  if ((unsigned)dst >= (unsigned)N) return;
  atomicAdd(&deg[dst], 1);
}

// ---------------- prep2: cvtx (blocks 0..CB-1) | scan1 (CB..) --------------
__global__ __launch_bounds__(256) void prep2_kernel(
    const float* __restrict__ x, const float* __restrict__ attWT,
    f16* __restrict__ xf, float* __restrict__ aS, float* __restrict__ aD,
    int n, int CB,
    const int* __restrict__ deg, int* __restrict__ tmp, int* __restrict__ bsum) {
  __shared__ int sd[256];
  const int t = threadIdx.x;
  if ((int)blockIdx.x >= CB) {  // ---- scan1 ----
    const int sb = blockIdx.x - CB;
    const int i = sb * 256 + t;
    int v = (i < n) ? deg[i] : 0;
    sd[t] = v;
    __syncthreads();
    for (int off = 1; off < 256; off <<= 1) {
      int u = (t >= off) ? sd[t - off] : 0;
      __syncthreads();
      sd[t] += u;
      __syncthreads();
    }
    if (i < n) tmp[i] = sd[t];
    if (t == 255) bsum[sb] = sd[255];
    return;
  }
  // ---- cvtx ----
  const int wv = t >> 6, lane = t & 63;
  float4 wr[8];
#pragma unroll
  for (int j = 0; j < 8; ++j) wr[j] = *(const float4*)&attWT[j * 256 + lane * 4];
  const int row0 = (blockIdx.x * 4 + wv) * 4;
#pragma unroll
  for (int r = 0; r < 4; ++r) {
    const int row = row0 + r;
    if (row >= n) return;
    const float4 v = *(const float4*)&x[(size_t)row * 256 + lane * 4];
    f16x4 o = {(f16)v.x, (f16)v.y, (f16)v.z, (f16)v.w};
    *(f16x4*)&xf[(size_t)row * 256 + lane * 4] = o;
    float p[8];
#pragma unroll
    for (int j = 0; j < 8; ++j)
      p[j] = v.x * wr[j].x + v.y * wr[j].y + v.z * wr[j].z + v.w * wr[j].w;
#pragma unroll
    for (int off = 32; off; off >>= 1)
#pragma unroll
      for (int j = 0; j < 8; ++j) p[j] += __shfl_xor(p[j], off);
    if (lane == 0) {
#pragma unroll
      for (int h = 0; h < 4; ++h) {
        aS[(size_t)row * 4 + h] = p[h * 2];
        aD[(size_t)row * 4 + h] = p[h * 2 + 1];
      }
    }
  }
}

// scan3 with fused block-offset reduction.
__global__ __launch_bounds__(256) void scan3_kernel(const int* __restrict__ deg,
                                                    const int* __restrict__ tmp,
                                                    const int* __restrict__ bsum,
                                                    int* __restrict__ row_ptr,
                                                    int* __restrict__ cursor, int n, int nb) {
  __shared__ int wsum[4];
  int v = 0;
  for (int t = threadIdx.x; t < nb; t += 256)
    if (t < (int)blockIdx.x) v += bsum[t];
#pragma unroll
  for (int off = 32; off; off >>= 1) v += __shfl_xor(v, off);
  if ((threadIdx.x & 63) == 0) wsum[threadIdx.x >> 6] = v;
  __syncthreads();
  const int boffb = wsum[0] + wsum[1] + wsum[2] + wsum[3];
  int i = blockIdx.x * 256 + threadIdx.x;
  if (i >= n) return;
  int g = tmp[i] + boffb;
  row_ptr[i + 1] = g;
  cursor[i] = g - deg[i];
  if (i == 0) row_ptr[0] = 0;
}

// scatter + fused alpha1: cse[pos] = {src, 0, alpha4(f16x4)}.
__global__ __launch_bounds__(256) void scatter_kernel(
    const int* __restrict__ ei, int E, int N,
    const float* __restrict__ aS, const float* __restrict__ aD,
    int* __restrict__ cursor, int4* __restrict__ cse) {
  const int flag = block_i64_flag(ei);
  int idx = blockIdx.x * blockDim.x + threadIdx.x;
  int EA = E + N;
  if (idx >= EA) return;
  int src, dst;
  if (idx < E) {
    if (flag) { src = ei[2 * (size_t)idx]; dst = ei[2 * ((size_t)E + idx)]; }
    else      { src = ei[(size_t)idx];     dst = ei[(size_t)E + idx]; }
  } else {
    src = dst = idx - E;
  }
  if ((unsigned)dst >= (unsigned)N || (unsigned)src >= (unsigned)N) return;
  const float4 s4 = *(const float4*)&aS[(size_t)src * 4];
  const float4 d4 = *(const float4*)&aD[(size_t)dst * 4];
  float x0 = s4.x + d4.x; x0 = (x0 > 0.f) ? x0 : 0.2f * x0;
  float x1 = s4.y + d4.y; x1 = (x1 > 0.f) ? x1 : 0.2f * x1;
  float x2 = s4.z + d4.z; x2 = (x2 > 0.f) ? x2 : 0.2f * x2;
  float x3 = s4.w + d4.w; x3 = (x3 > 0.f) ? x3 : 0.2f * x3;
  f16x4 a = {(f16)__expf(x0), (f16)__expf(x1), (f16)__expf(x2), (f16)__expf(x3)};
  const int2 ab = *(const int2*)&a;
  int pos = atomicAdd(&cursor[dst], 1);
  int4 w;
  w.x = src; w.y = 0; w.z = ab.x; w.w = ab.y;
  cse[pos] = w;
}

// ------------------- layer-1 x-space aggregation (per dst) -----------------
// r15 grid (1 dst/wave, dynamic blocks). Edge records are wave-uniform ->
// broadcast via readlane into SGPRs (no LDS, no lgkm waits); pair-alpha
// packing on SALU; x-gathers use scalar-base addressing.
__global__ __launch_bounds__(256) void agg1_kernel(
    const int* __restrict__ row_ptr, const int4* __restrict__ cse,
    const f16* __restrict__ xf, f16* __restrict__ aggX, int n) {
  const int wv = threadIdx.x >> 6, lane = threadIdx.x & 63;
  const int dst = blockIdx.x * 4 + wv;
  if (dst >= n) return;
  const int beg = row_ptr[dst], end = row_ptr[dst + 1];
  f32x4 den4 = {0.f, 0.f, 0.f, 0.f};
  float acc[16];
#pragma unroll
  for (int q = 0; q < 16; ++q) acc[q] = 0.f;
  const f16* __restrict__ xcol = xf + lane * 4;

  for (int base = beg; base < end; base += 64) {
    int i = base + lane;
    int4 w = make_int4(0, 0, 0, 0);  // alpha bits 0 -> +0.0h
    if (i < end) w = cse[i];
    const f16x2 dz = *(const f16x2*)&w.z;
    const f16x2 dw = *(const f16x2*)&w.w;
    den4[0] += (float)dz[0]; den4[1] += (float)dz[1];
    den4[2] += (float)dw[0]; den4[3] += (float)dw[1];
    const int m = min(64, end - base);
    const int np = (m + 1) >> 1;   // pairs (odd tail pair has alpha=0 slot)
    const int fullp = np & ~3;     // 4-pair (8-edge) batches
    int p = 0;
    for (; p < fullp; p += 4) {
      int s[8];
      unsigned az[8], aw[8];
#pragma unroll
      for (int k = 0; k < 8; ++k) {
        const int ln = 2 * p + k;
        s[k]  = __builtin_amdgcn_readlane(w.x, ln);
        az[k] = (unsigned)__builtin_amdgcn_readlane(w.z, ln);
        aw[k] = (unsigned)__builtin_amdgcn_readlane(w.w, ln);
      }
      f16x4 v[8];
#pragma unroll
      for (int k = 0; k < 8; ++k)
        v[k] = *(const f16x4*)&xcol[(size_t)s[k] * 256];
#pragma unroll
      for (int k = 0; k < 4; ++k) {
        const unsigned z0 = az[2 * k], z1 = az[2 * k + 1];
        const unsigned w0 = aw[2 * k], w1 = aw[2 * k + 1];
        const f16x2 b0 = u2h((z0 & 0xFFFFu) | (z1 << 16));
        const f16x2 b1 = u2h((z0 >> 16) | (z1 & 0xFFFF0000u));
        const f16x2 b2 = u2h((w0 & 0xFFFFu) | (w1 << 16));
        const f16x2 b3 = u2h((w0 >> 16) | (w1 & 0xFFFF0000u));
#pragma unroll
        for (int c = 0; c < 4; ++c) {
          const f16x2 xp = {v[2 * k][c], v[2 * k + 1][c]};
          acc[c]      = dot2f(xp, b0, acc[c]);
          acc[4 + c]  = dot2f(xp, b1, acc[4 + c]);
          acc[8 + c]  = dot2f(xp, b2, acc[8 + c]);
          acc[12 + c] = dot2f(xp, b3, acc[12 + c]);
        }
      }
    }
    for (; p < np; ++p) {  // wave-uniform tail, 0..3 pairs
      const int ln0 = 2 * p, ln1 = 2 * p + 1;
      const int s0 = __builtin_amdgcn_readlane(w.x, ln0);
      const int s1 = __builtin_amdgcn_readlane(w.x, ln1);
      const unsigned z0 = (unsigned)__builtin_amdgcn_readlane(w.z, ln0);
      const unsigned z1 = (unsigned)__builtin_amdgcn_readlane(w.z, ln1);
      const unsigned w0 = (unsigned)__builtin_amdgcn_readlane(w.w, ln0);
      const unsigned w1 = (unsigned)__builtin_amdgcn_readlane(w.w, ln1);
      const f16x4 v0 = *(const f16x4*)&xcol[(size_t)s0 * 256];
      const f16x4 v1 = *(const f16x4*)&xcol[(size_t)s1 * 256];
      const f16x2 b0 = u2h((z0 & 0xFFFFu) | (z1 << 16));
      const f16x2 b1 = u2h((z0 >> 16) | (z1 & 0xFFFF0000u));
      const f16x2 b2 = u2h((w0 & 0xFFFFu) | (w1 << 16));
      const f16x2 b3 = u2h((w0 >> 16) | (w1 & 0xFFFF0000u));
#pragma unroll
      for (int c = 0; c < 4; ++c) {
        const f16x2 xp = {v0[c], v1[c]};
        acc[c]      = dot2f(xp, b0, acc[c]);
        acc[4 + c]  = dot2f(xp, b1, acc[4 + c]);
        acc[8 + c]  = dot2f(xp, b2, acc[8 + c]);
        acc[12 + c] = dot2f(xp, b3, acc[12 + c]);
      }
    }
  }
#pragma unroll
  for (int off = 32; off; off >>= 1) {
#pragma unroll
    for (int k = 0; k < 4; ++k) den4[k] += __shfl_xor(den4[k], off);
  }
  const float inv[4] = {1.f / den4[0], 1.f / den4[1], 1.f / den4[2], 1.f / den4[3]};
#pragma unroll
  for (int h = 0; h < 4; ++h) {
    f16x4 o = {(f16)(acc[h * 4 + 0] * inv[h]), (f16)(acc[h * 4 + 1] * inv[h]),
               (f16)(acc[h * 4 + 2] * inv[h]), (f16)(acc[h * 4 + 3] * inv[h])};
    *(f16x4*)&aggX[(size_t)dst * 1024 + h * 256 + lane * 4] = o;
  }
}

// ---------------- GEMM1 per head: A2 = elu(aggX_h @ W1_h^T + b1) -----------
__global__ __launch_bounds__(256) void gemm1_kernel(
    const f16* __restrict__ A, const f16* __restrict__ Bm,
    const float* __restrict__ bias, f16* __restrict__ C, int Nrows) {
  __shared__ f16 lA[128 * 32];
  __shared__ f16 lB[128 * 32];
  const int h = blockIdx.x;
  const int tid = threadIdx.x;
  const int w = tid >> 6, lane = tid & 63;
  const int wm = w >> 1, wn = w & 1;
  const int rowBase = blockIdx.y * 128;
  const int lrow = lane & 15, lk = lane >> 4;
  f32x4 acc[4][4];
#pragma unroll
  for (int i = 0; i < 4; ++i)
#pragma unroll
    for (int j = 0; j < 4; ++j) acc[i][j] = (f32x4){0.f, 0.f, 0.f, 0.f};

  for (int kv = 0; kv < 256; kv += 32) {
    f16x8 stA[2], stB[2];
#pragma unroll
    for (int s = 0; s < 2; ++s) {
      int q = s * 256 + tid;
      int r = q >> 2;
      int cs = (q & 3) ^ ((r >> 1) & 3);
      int row = rowBase + r;
      if (row >= Nrows) row = Nrows - 1;  // clamp: pad outputs unused
      stA[s] = *(const f16x8*)(A + (size_t)row * 1024 + h * 256 + kv + cs * 8);
    }
#pragma unroll
    for (int s = 0; s < 2; ++s) {
      int q = s * 256 + tid;
      int r = q >> 2;
      int cs = (q & 3) ^ ((r >> 1) & 3);
      stB[s] = *(const f16x8*)(Bm + (size_t)(h * 128 + r) * 256 + kv + cs * 8);
    }
#pragma unroll
    for (int s = 0; s < 2; ++s) *(f16x8*)&lA[(size_t)(s * 256 + tid) * 8] = stA[s];
#pragma unroll
    for (int s = 0; s < 2; ++s) *(f16x8*)&lB[(size_t)(s * 256 + tid) * 8] = stB[s];
    __syncthreads();
    f16x8 aF[4], bF[4];
#pragma unroll
    for (int i = 0; i < 4; ++i) {
      int ra = wm * 64 + i * 16 + lrow;
      aF[i] = *(const f16x8*)&lA[(ra * 4 + (lk ^ ((ra >> 1) & 3))) * 8];
      int rb = wn * 64 + i * 16 + lrow;
      bF[i] = *(const f16x8*)&lB[(rb * 4 + (lk ^ ((rb >> 1) & 3))) * 8];
    }
#pragma unroll
    for (int i = 0; i < 4; ++i)
#pragma unroll
      for (int j = 0; j < 4; ++j)
        acc[i][j] = __builtin_amdgcn_mfma_f32_16x16x32_f16(aF[i], bF[j], acc[i][j], 0, 0, 0);
    __syncthreads();
  }
  // epilogue: bias + ELU, store f16 (C/D layout: col=lane&15, row=(lane>>4)*4+reg)
  float bj[4];
#pragma unroll
  for (int j = 0; j < 4; ++j) bj[j] = bias[h * 128 + wn * 64 + j * 16 + lrow];
#pragma unroll
  for (int i = 0; i < 4; ++i) {
    int row0 = rowBase + wm * 64 + i * 16 + lk * 4;
#pragma unroll
    for (int j = 0; j < 4; ++j) {
      int col = h * 128 + wn * 64 + j * 16 + lrow;
#pragma unroll
      for (int rr = 0; rr < 4; ++rr) {
        float vv = acc[i][j][rr] + bj[j];
        vv = (vv > 0.f) ? vv : (__expf(vv) - 1.f);
        C[(size_t)(row0 + rr) * 512 + col] = (f16)vv;
      }
    }
  }
}

// ------------- GEMM2 (BM=64, TPB=256, wave-tile 32x64) + fused attn2 -------
__global__ __launch_bounds__(256) void gemm2_kernel(
    const f16* __restrict__ A, const f16* __restrict__ Bm, f16* __restrict__ C,
    const float* __restrict__ attS, const float* __restrict__ attD,
    float* __restrict__ aS, float* __restrict__ aD,
    int K, int Ncols, int Nrows) {
  __shared__ f16 lA[64 * 32];
  __shared__ f16 lB[128 * 32];
  const int tid = threadIdx.x;
  const int w = tid >> 6, lane = tid & 63;
  const int wm = w >> 1, wn = w & 1;
  const int rowBase = blockIdx.y * 64;
  const int lrow = lane & 15, lk = lane >> 4;
  f32x4 acc[2][4];
#pragma unroll
  for (int i = 0; i < 2; ++i)
#pragma unroll
    for (int j = 0; j < 4; ++j) acc[i][j] = (f32x4){0.f, 0.f, 0.f, 0.f};

  for (int kv = 0; kv < K; kv += 32) {
    f16x8 stA, stB[2];
    {
      int q = tid;
      int r = q >> 2;
      int cs = (q & 3) ^ ((r >> 1) & 3);
      stA = *(const f16x8*)(A + (size_t)(rowBase + r) * K + kv + cs * 8);
    }
#pragma unroll
    for (int s = 0; s < 2; ++s) {
      int q = s * 256 + tid;
      int r = q >> 2;
      int cs = (q & 3) ^ ((r >> 1) & 3);
      stB[s] = *(const f16x8*)(Bm + (size_t)r * K + kv + cs * 8);
    }
    *(f16x8*)&lA[(size_t)tid * 8] = stA;
#pragma unroll
    for (int s = 0; s < 2; ++s) *(f16x8*)&lB[(size_t)(s * 256 + tid) * 8] = stB[s];
    __syncthreads();
    f16x8 aF[2], bF[4];
#pragma unroll
    for (int i = 0; i < 2; ++i) {
      int ra = wm * 32 + i * 16 + lrow;
      aF[i] = *(const f16x8*)&lA[(ra * 4 + (lk ^ ((ra >> 1) & 3))) * 8];
    }
#pragma unroll
    for (int j = 0; j < 4; ++j) {
      int rb = wn * 64 + j * 16 + lrow;
      bF[j] = *(const f16x8*)&lB[(rb * 4 + (lk ^ ((rb >> 1) & 3))) * 8];
    }
#pragma unroll
    for (int i = 0; i < 2; ++i)
#pragma unroll
      for (int j = 0; j < 4; ++j)
        acc[i][j] = __builtin_amdgcn_mfma_f32_16x16x32_f16(aF[i], bF[j], acc[i][j], 0, 0, 0);
    __syncthreads();
  }
#pragma unroll
  for (int i = 0; i < 2; ++i) {
    int row0 = rowBase + wm * 32 + i * 16 + lk * 4;
#pragma unroll
    for (int j = 0; j < 4; ++j) {
      int col = wn * 64 + j * 16 + lrow;
#pragma unroll
      for (int rr = 0; rr < 4; ++rr)
        C[(size_t)(row0 + rr) * Ncols + col] = (f16)acc[i][j][rr];
    }
  }
  // Fused attn2 epilogue (H=1): rows split by wm, cols by wn.
  float sv[4], dv[4];
#pragma unroll
  for (int j = 0; j < 4; ++j) {
    int cl = wn * 64 + j * 16 + lrow;
    sv[j] = attS[cl];
    dv[j] = attD[cl];
  }
  __shared__ float sred[2][2][32][2];
#pragma unroll
  for (int i = 0; i < 2; ++i) {
#pragma unroll
    for (int rr = 0; rr < 4; ++rr) {
      float ps = 0.f, pd = 0.f;
#pragma unroll
      for (int j = 0; j < 4; ++j) {
        ps = fmaf(acc[i][j][rr], sv[j], ps);
        pd = fmaf(acc[i][j][rr], dv[j], pd);
      }
#pragma unroll
      for (int off = 1; off < 16; off <<= 1) {
        ps += __shfl_xor(ps, off);
        pd += __shfl_xor(pd, off);
      }
      if (lrow == 0) {
        int rloc = i * 16 + lk * 4 + rr;
        sred[wm][wn][rloc][0] = ps;
        sred[wm][wn][rloc][1] = pd;
      }
    }
  }
  __syncthreads();
  if (tid < 64) {
    int row = rowBase + tid;
    if (row < Nrows) {
      int m = tid >> 5, rl = tid & 31;
      aS[row] = sred[m][0][rl][0] + sred[m][1][rl][0];
      aD[row] = sred[m][0][rl][1] + sred[m][1][rl][1];
    }
  }
}

// ------------- layer-2 aggregation + ELU + fused classifier ----------------
__global__ __launch_bounds__(256) void agg2_kernel(
    const int* __restrict__ row_ptr, const int4* __restrict__ cse,
    const float* __restrict__ aS, const float* __restrict__ aD,
    const f16* __restrict__ xw2, const float* __restrict__ b2,
    const float* __restrict__ Wc, const float* __restrict__ bc,
    float* __restrict__ out, int n) {
  __shared__ __align__(16) float2 led[4][64];
  const int wv = threadIdx.x >> 6, lane = threadIdx.x & 63;
  const int dst = blockIdx.x * 4 + wv;
  if (dst >= n) return;
  const int beg = row_ptr[dst], end = row_ptr[dst + 1];
  const int half = lane >> 5, lc = lane & 31;
  const float ad = aD[dst];
  float den = 0.f;
  float acc[4] = {0.f, 0.f, 0.f, 0.f};
  const f16* __restrict__ xrow = xw2 + lc * 4;

  for (int base = beg; base < end; base += 64) {
    int i = base + lane;
    float2 pa = make_float2(__int_as_float(0), 0.f);
    if (i < end) {
      int s = cse[i].x;
      float x = aS[s] + ad;
      x = (x > 0.f) ? x : 0.2f * x;
      pa = make_float2(__int_as_float(s), __expf(x));
    }
    den += pa.y;
    led[wv][lane] = pa;
    asm volatile("s_waitcnt lgkmcnt(0)" ::: "memory");
    const int m = min(64, end - base);
    const int np2 = (m + 1) >> 1;
    int p = 0;
    for (; p < (np2 & ~7); p += 8) {
      int sj[8];
      float aj[8];
      f16x4 v[8];
#pragma unroll
      for (int k = 0; k < 8; ++k) {
        float2 q = led[wv][(p + k) * 2 + half];
        sj[k] = __float_as_int(q.x);
        aj[k] = q.y;
      }
#pragma unroll
      for (int k = 0; k < 8; ++k) v[k] = *(const f16x4*)&xrow[(size_t)sj[k] * 128];
#pragma unroll
      for (int k = 0; k < 8; ++k) {
        acc[0] = fmaf(aj[k], (float)v[k][0], acc[0]);
        acc[1] = fmaf(aj[k], (float)v[k][1], acc[1]);
        acc[2] = fmaf(aj[k], (float)v[k][2], acc[2]);
        acc[3] = fmaf(aj[k], (float)v[k][3], acc[3]);
      }
    }
    for (; p < np2; ++p) {
      const float2 q = led[wv][p * 2 + half];
      const int s = __float_as_int(q.x);
      const float a = q.y;
      const f16x4 vv = *(const f16x4*)&xrow[(size_t)s * 128];
      acc[0] = fmaf(a, (float)vv[0], acc[0]);
      acc[1] = fmaf(a, (float)vv[1], acc[1]);
      acc[2] = fmaf(a, (float)vv[2], acc[2]);
      acc[3] = fmaf(a, (float)vv[3], acc[3]);
    }
  }
#pragma unroll
  for (int off = 32; off; off >>= 1) den += __shfl_xor(den, off);
  const float inv = 1.f / den;
#pragma unroll
  for (int k = 0; k < 4; ++k) acc[k] += __shfl_xor(acc[k], 32);
  const int c = lc * 4;
  const float4 bb = *(const float4*)&b2[c];
  const float4 w0 = *(const float4*)&Wc[c];
  const float4 w1 = *(const float4*)&Wc[128 + c];
  const float bv[4] = {bb.x, bb.y, bb.z, bb.w};
  const float w0v[4] = {w0.x, w0.y, w0.z, w0.w};
  const float w1v[4] = {w1.x, w1.y, w1.z, w1.w};
  float l0 = 0.f, l1 = 0.f;
#pragma unroll
  for (int k = 0; k < 4; ++k) {
    float vv = acc[k] * inv + bv[k];
    vv = (vv > 0.f) ? vv : (__expf(vv) - 1.f);
    l0 = fmaf(vv, w0v[k], l0);
    l1 = fmaf(vv, w1v[k], l1);
  }
#pragma unroll
  for (int off = 16; off; off >>= 1) {
    l0 += __shfl_xor(l0, off);
    l1 += __shfl_xor(l1, off);
  }
  if (lane == 0) {
    out[dst * 2] = l0 + bc[0];
    out[dst * 2 + 1] = l1 + bc[1];
  }
}

// ---------------------------------------------------------------------------

extern "C" void kernel_launch(void* const* d_in, const int* in_sizes, int n_in,
                              void* d_out, int out_size, void* d_ws, size_t ws_size,
                              hipStream_t stream) {
  const float* x     = (const float*)d_in[0];
  const int*   ei    = (const int*)d_in[1];
  const float* W1    = (const float*)d_in[2];
  const float* att1s = (const float*)d_in[3];
  const float* att1d = (const float*)d_in[4];
  const float* b1    = (const float*)d_in[5];
  const float* W2    = (const float*)d_in[6];
  const float* att2s = (const float*)d_in[7];
  const float* att2d = (const float*)d_in[8];
  const float* b2    = (const float*)d_in[9];
  const float* Wc    = (const float*)d_in[10];
  const float* bc    = (const float*)d_in[11];
  float* out = (float*)d_out;

  const int N = in_sizes[0] / 256;
  const int E = in_sizes[1] / 2;
  const int EA = E + N;
  const int Mpad = (N + 127) & ~127;
  const int NB = (N + 255) / 256;
  const int EB = (EA + 255) / 256;
  const int CB = (N + 15) / 16;

  char* base = (char*)d_ws;
  size_t off = 0;
  auto alloc = [&](size_t bytes) -> char* {
    char* p = base + off;
    off = (off + bytes + 255) & ~(size_t)255;
    return p;
  };
  f16* aggX = (f16*)alloc((size_t)Mpad * 1024 * sizeof(f16));  // x-space agg (4 heads)
  f16* xf   = (f16*)alloc((size_t)Mpad * 256 * sizeof(f16));   // x in f16
  f16* B1f  = (f16*)alloc((size_t)512 * 256 * sizeof(f16));    // W1 f16
  f16* A2   = (f16*)alloc((size_t)Mpad * 512 * sizeof(f16));   // h = elu(layer1)
  f16* B2f  = (f16*)alloc((size_t)128 * 512 * sizeof(f16));    // W2 f16
  f16* xw2h = (f16*)alloc((size_t)Mpad * 128 * sizeof(f16));   // layer2 pre-agg
  float* attWT = (float*)alloc((size_t)8 * 256 * sizeof(float));
  float* aS1 = (float*)alloc((size_t)N * 4 * sizeof(float));
  float* aD1 = (float*)alloc((size_t)N * 4 * sizeof(float));
  float* aS2 = (float*)alloc((size_t)N * sizeof(float));
  float* aD2 = (float*)alloc((size_t)N * sizeof(float));
  int* deg     = (int*)alloc((size_t)N * sizeof(int));
  int* row_ptr = (int*)alloc((size_t)(N + 1) * sizeof(int));
  int* cursor  = (int*)alloc((size_t)N * sizeof(int));
  int4* cse    = (int4*)alloc((size_t)EA * sizeof(int4));  // {src,0,alpha4 f16x4}
  int* tmp     = (int*)alloc((size_t)N * sizeof(int));
  int* bsum    = (int*)alloc((size_t)NB * sizeof(int));
  (void)n_in; (void)out_size; (void)ws_size;

  hipMemsetAsync(deg, 0, (size_t)N * sizeof(int), stream);
  if (Mpad > N)  // zero A2 pad rows so GEMM2 pad outputs stay finite
    hipMemsetAsync(A2 + (size_t)N * 512, 0, (size_t)(Mpad - N) * 512 * sizeof(f16), stream);

  // prep1: attw (4) | cvtw (192) | hist (EB)   -- attw latency hidden
  prep1_kernel<<<196 + EB, 256, 0, stream>>>(W1, att1s, att1d, attWT,
                                             B1f, W2, B2f, ei, E, N, deg);
  // prep2: cvtx (CB) | scan1 (NB)
  prep2_kernel<<<CB + NB, 256, 0, stream>>>(x, attWT, xf, aS1, aD1, N, CB,
                                            deg, tmp, bsum);
  scan3_kernel<<<NB, 256, 0, stream>>>(deg, tmp, bsum, row_ptr, cursor, N, NB);
  scatter_kernel<<<EB, 256, 0, stream>>>(ei, E, N, aS1, aD1, cursor, cse);

  agg1_kernel<<<(N + 3) / 4, 256, 0, stream>>>(row_ptr, cse, xf, aggX, N);

  dim3 g1(4, Mpad / 128);
  gemm1_kernel<<<g1, 256, 0, stream>>>(aggX, B1f, b1, A2, N);

  dim3 g2(1, Mpad / 64);
  gemm2_kernel<<<g2, 256, 0, stream>>>(A2, B2f, xw2h, att2s, att2d, aS2, aD2, 512, 128, N);

  agg2_kernel<<<(N + 3) / 4, 256, 0, stream>>>(row_ptr, cse, aS2, aD2, xw2h, b2, Wc, bc, out, N);
}

// Round 10
// 373.396 us; speedup vs baseline: 1.0459x; 1.0111x over previous
//
#include <hip/hip_runtime.h>
#include <stdint.h>

// ---------------------------------------------------------------------------
// GAT bot detector, 2-layer, N=50000 E=800000 IN=256 HID=128 HEADS=4.
// Round 19: r15 base restored (best, 376.3us; r16/r17/r18 structural
// variants all flat-or-worse -- agg1 is invariant at 4.1-4.25 TB/s across
// 5 variants => gather-pattern HBM floor, ~72us). One audited removal:
// A2 pad memset is redundant (gemm1's grid writes ALL Mpad rows; clamp only
// affects aggX reads; pad outputs never propagate: cse[].x < N guaranteed,
// aS2/aD2 writes guarded). -1 dispatch.
// ---------------------------------------------------------------------------

typedef _Float16 f16;
typedef f16 f16x8 __attribute__((ext_vector_type(8)));
typedef f16 f16x4 __attribute__((ext_vector_type(4)));
typedef f16 f16x2 __attribute__((ext_vector_type(2)));
typedef float f32x4 __attribute__((ext_vector_type(4)));

#if defined(__has_builtin)
#if __has_builtin(__builtin_amdgcn_fdot2)
#define HAS_FDOT2 1
#endif
#endif
#ifndef HAS_FDOT2
#define HAS_FDOT2 0
#endif

__device__ __forceinline__ float dot2f(f16x2 a, f16x2 b, float c) {
#if HAS_FDOT2
  return __builtin_amdgcn_fdot2(a, b, c, false);
#else
  return fmaf((float)a[0], (float)b[0], fmaf((float)a[1], (float)b[1], c));
#endif
}

// i64-layout ballot, per-block (wave 0).
__device__ __forceinline__ int block_i64_flag(const int* __restrict__ ei) {
  __shared__ int sflag;
  if (threadIdx.x < 64) {
    int nz = 0;
#pragma unroll
    for (int w = 0; w < 4; ++w) nz |= ei[2 * (threadIdx.x * 4 + w) + 1];
    unsigned long long b = __ballot(nz != 0);
    if (threadIdx.x == 0) sflag = (b == 0ull) ? 1 : 0;
  }
  __syncthreads();
  return sflag;
}

// ---------------- prep1: attw (blocks 0..3) | cvtw (4..195) | hist ---------
__global__ __launch_bounds__(256) void prep1_kernel(
    const float* __restrict__ W1, const float* __restrict__ s1,
    const float* __restrict__ d1, float* __restrict__ attWT,
    f16* __restrict__ B1f, const float* __restrict__ W2, f16* __restrict__ B2f,
    const int* __restrict__ ei, int E, int N, int* __restrict__ deg) {
  const int b = blockIdx.x;
  const int tid = threadIdx.x;
  if (b < 4) {  // ---- attw ----
    const int h = b, c = tid;
    float ps = 0.f, pd = 0.f;
    for (int k = 0; k < 128; ++k) {
      float w = W1[(size_t)(h * 128 + k) * 256 + c];
      ps = fmaf(w, s1[h * 128 + k], ps);
      pd = fmaf(w, d1[h * 128 + k], pd);
    }
    attWT[(h * 2 + 0) * 256 + c] = ps;
    attWT[(h * 2 + 1) * 256 + c] = pd;
    return;
  }
  if (b < 196) {  // ---- cvtw ----
    int idx = (b - 4) * 256 + tid;
    const float* src;
    f16* dst;
    int j;
    if (idx < 32768) { src = W1; dst = B1f; j = idx; }
    else { src = W2; dst = B2f; j = idx - 32768; }
    float4 v = *(const float4*)&src[(size_t)j * 4];
    f16x4 o = {(f16)v.x, (f16)v.y, (f16)v.z, (f16)v.w};
    *(f16x4*)&dst[(size_t)j * 4] = o;
    return;
  }
  // ---- hist ----
  const int flag = block_i64_flag(ei);
  int idx = (b - 196) * 256 + tid;
  int EA = E + N;
  if (idx >= EA) return;
  int dst;
  if (idx < E) {
    dst = flag ? ei[2 * ((size_t)E + idx)] : ei[(size_t)E + idx];
  } else {
    dst = idx - E;  // self loop
  }
  if ((unsigned)dst >= (unsigned)N) return;
  atomicAdd(&deg[dst], 1);
}

// ---------------- prep2: cvtx (blocks 0..CB-1) | scan1 (CB..) --------------
__global__ __launch_bounds__(256) void prep2_kernel(
    const float* __restrict__ x, const float* __restrict__ attWT,
    f16* __restrict__ xf, float* __restrict__ aS, float* __restrict__ aD,
    int n, int CB,
    const int* __restrict__ deg, int* __restrict__ tmp, int* __restrict__ bsum) {
  __shared__ int sd[256];
  const int t = threadIdx.x;
  if ((int)blockIdx.x >= CB) {  // ---- scan1 ----
    const int sb = blockIdx.x - CB;
    const int i = sb * 256 + t;
    int v = (i < n) ? deg[i] : 0;
    sd[t] = v;
    __syncthreads();
    for (int off = 1; off < 256; off <<= 1) {
      int u = (t >= off) ? sd[t - off] : 0;
      __syncthreads();
      sd[t] += u;
      __syncthreads();
    }
    if (i < n) tmp[i] = sd[t];
    if (t == 255) bsum[sb] = sd[255];
    return;
  }
  // ---- cvtx ----
  const int wv = t >> 6, lane = t & 63;
  float4 wr[8];
#pragma unroll
  for (int j = 0; j < 8; ++j) wr[j] = *(const float4*)&attWT[j * 256 + lane * 4];
  const int row0 = (blockIdx.x * 4 + wv) * 4;
#pragma unroll
  for (int r = 0; r < 4; ++r) {
    const int row = row0 + r;
    if (row >= n) return;
    const float4 v = *(const float4*)&x[(size_t)row * 256 + lane * 4];
    f16x4 o = {(f16)v.x, (f16)v.y, (f16)v.z, (f16)v.w};
    *(f16x4*)&xf[(size_t)row * 256 + lane * 4] = o;
    float p[8];
#pragma unroll
    for (int j = 0; j < 8; ++j)
      p[j] = v.x * wr[j].x + v.y * wr[j].y + v.z * wr[j].z + v.w * wr[j].w;
#pragma unroll
    for (int off = 32; off; off >>= 1)
#pragma unroll
      for (int j = 0; j < 8; ++j) p[j] += __shfl_xor(p[j], off);
    if (lane == 0) {
#pragma unroll
      for (int h = 0; h < 4; ++h) {
        aS[(size_t)row * 4 + h] = p[h * 2];
        aD[(size_t)row * 4 + h] = p[h * 2 + 1];
      }
    }
  }
}

// scan3 with fused block-offset reduction.
__global__ __launch_bounds__(256) void scan3_kernel(const int* __restrict__ deg,
                                                    const int* __restrict__ tmp,
                                                    const int* __restrict__ bsum,
                                                    int* __restrict__ row_ptr,
                                                    int* __restrict__ cursor, int n, int nb) {
  __shared__ int wsum[4];
  int v = 0;
  for (int t = threadIdx.x; t < nb; t += 256)
    if (t < (int)blockIdx.x) v += bsum[t];
#pragma unroll
  for (int off = 32; off; off >>= 1) v += __shfl_xor(v, off);
  if ((threadIdx.x & 63) == 0) wsum[threadIdx.x >> 6] = v;
  __syncthreads();
  const int boffb = wsum[0] + wsum[1] + wsum[2] + wsum[3];
  int i = blockIdx.x * 256 + threadIdx.x;
  if (i >= n) return;
  int g = tmp[i] + boffb;
  row_ptr[i + 1] = g;
  cursor[i] = g - deg[i];
  if (i == 0) row_ptr[0] = 0;
}

// scatter + fused alpha1: cse[pos] = {src, 0, alpha4(f16x4)}.
__global__ __launch_bounds__(256) void scatter_kernel(
    const int* __restrict__ ei, int E, int N,
    const float* __restrict__ aS, const float* __restrict__ aD,
    int* __restrict__ cursor, int4* __restrict__ cse) {
  const int flag = block_i64_flag(ei);
  int idx = blockIdx.x * blockDim.x + threadIdx.x;
  int EA = E + N;
  if (idx >= EA) return;
  int src, dst;
  if (idx < E) {
    if (flag) { src = ei[2 * (size_t)idx]; dst = ei[2 * ((size_t)E + idx)]; }
    else      { src = ei[(size_t)idx];     dst = ei[(size_t)E + idx]; }
  } else {
    src = dst = idx - E;
  }
  if ((unsigned)dst >= (unsigned)N || (unsigned)src >= (unsigned)N) return;
  const float4 s4 = *(const float4*)&aS[(size_t)src * 4];
  const float4 d4 = *(const float4*)&aD[(size_t)dst * 4];
  float x0 = s4.x + d4.x; x0 = (x0 > 0.f) ? x0 : 0.2f * x0;
  float x1 = s4.y + d4.y; x1 = (x1 > 0.f) ? x1 : 0.2f * x1;
  float x2 = s4.z + d4.z; x2 = (x2 > 0.f) ? x2 : 0.2f * x2;
  float x3 = s4.w + d4.w; x3 = (x3 > 0.f) ? x3 : 0.2f * x3;
  f16x4 a = {(f16)__expf(x0), (f16)__expf(x1), (f16)__expf(x2), (f16)__expf(x3)};
  const int2 ab = *(const int2*)&a;
  int pos = atomicAdd(&cursor[dst], 1);
  int4 w;
  w.x = src; w.y = 0; w.z = ab.x; w.w = ab.y;
  cse[pos] = w;
}

// ------------------- layer-1 x-space aggregation (per dst) -----------------
// One wave per dst, dynamic blocks (r15 proven). Staging = one coalesced 16B
// cse load; dot2 pairs; 4-pair batches + wave-uniform tail.
__global__ __launch_bounds__(256) void agg1_kernel(
    const int* __restrict__ row_ptr, const int4* __restrict__ cse,
    const f16* __restrict__ xf, f16* __restrict__ aggX, int n) {
  __shared__ __align__(16) int4 lent[4][64];
  const int wv = threadIdx.x >> 6, lane = threadIdx.x & 63;
  const int dst = blockIdx.x * 4 + wv;
  if (dst >= n) return;
  const int beg = row_ptr[dst], end = row_ptr[dst + 1];
  f32x4 den4 = {0.f, 0.f, 0.f, 0.f};
  float acc[16];
#pragma unroll
  for (int q = 0; q < 16; ++q) acc[q] = 0.f;
  const f16* __restrict__ xcol = xf + lane * 4;

  for (int base = beg; base < end; base += 64) {
    int i = base + lane;
    int4 w = make_int4(0, 0, 0, 0);  // alpha bits 0 -> +0.0h
    if (i < end) w = cse[i];
    const f16x2 dz = *(const f16x2*)&w.z;
    const f16x2 dw = *(const f16x2*)&w.w;
    den4[0] += (float)dz[0]; den4[1] += (float)dz[1];
    den4[2] += (float)dw[0]; den4[3] += (float)dw[1];
    lent[wv][lane] = w;
    asm volatile("s_waitcnt lgkmcnt(0)" ::: "memory");
    const int m = min(64, end - base);
    const int np = (m + 1) >> 1;   // pairs (odd tail pair has alpha=0 slot)
    const int fullp = np & ~3;     // 4-pair batches
    int p = 0;
    for (; p < fullp; p += 4) {
      int4 e0[4], e1[4];
      f16x4 v[8];
#pragma unroll
      for (int k = 0; k < 4; ++k) {
        e0[k] = lent[wv][2 * (p + k)];
        e1[k] = lent[wv][2 * (p + k) + 1];
      }
#pragma unroll
      for (int k = 0; k < 4; ++k) {
        v[2 * k]     = *(const f16x4*)&xcol[(size_t)e0[k].x * 256];
        v[2 * k + 1] = *(const f16x4*)&xcol[(size_t)e1[k].x * 256];
      }
#pragma unroll
      for (int k = 0; k < 4; ++k) {
        const f16x2 q00 = *(const f16x2*)&e0[k].z, q01 = *(const f16x2*)&e0[k].w;
        const f16x2 q10 = *(const f16x2*)&e1[k].z, q11 = *(const f16x2*)&e1[k].w;
        const f16x2 b0 = {q00[0], q10[0]}, b1 = {q00[1], q10[1]},
                    b2 = {q01[0], q11[0]}, b3 = {q01[1], q11[1]};
#pragma unroll
        for (int c = 0; c < 4; ++c) {
          const f16x2 xp = {v[2 * k][c], v[2 * k + 1][c]};
          acc[c]      = dot2f(xp, b0, acc[c]);
          acc[4 + c]  = dot2f(xp, b1, acc[4 + c]);
          acc[8 + c]  = dot2f(xp, b2, acc[8 + c]);
          acc[12 + c] = dot2f(xp, b3, acc[12 + c]);
        }
      }
    }
    for (; p < np; ++p) {  // wave-uniform tail, 0..3 pairs
      const int4 e0 = lent[wv][2 * p];
      const int4 e1 = lent[wv][2 * p + 1];
      const f16x4 v0 = *(const f16x4*)&xcol[(size_t)e0.x * 256];
      const f16x4 v1 = *(const f16x4*)&xcol[(size_t)e1.x * 256];
      const f16x2 q00 = *(const f16x2*)&e0.z, q01 = *(const f16x2*)&e0.w;
      const f16x2 q10 = *(const f16x2*)&e1.z, q11 = *(const f16x2*)&e1.w;
      const f16x2 b0 = {q00[0], q10[0]}, b1 = {q00[1], q10[1]},
                  b2 = {q01[0], q11[0]}, b3 = {q01[1], q11[1]};
#pragma unroll
      for (int c = 0; c < 4; ++c) {
        const f16x2 xp = {v0[c], v1[c]};
        acc[c]      = dot2f(xp, b0, acc[c]);
        acc[4 + c]  = dot2f(xp, b1, acc[4 + c]);
        acc[8 + c]  = dot2f(xp, b2, acc[8 + c]);
        acc[12 + c] = dot2f(xp, b3, acc[12 + c]);
      }
    }
  }
#pragma unroll
  for (int off = 32; off; off >>= 1) {
#pragma unroll
    for (int k = 0; k < 4; ++k) den4[k] += __shfl_xor(den4[k], off);
  }
  const float inv[4] = {1.f / den4[0], 1.f / den4[1], 1.f / den4[2], 1.f / den4[3]};
#pragma unroll
  for (int h = 0; h < 4; ++h) {
    f16x4 o = {(f16)(acc[h * 4 + 0] * inv[h]), (f16)(acc[h * 4 + 1] * inv[h]),
               (f16)(acc[h * 4 + 2] * inv[h]), (f16)(acc[h * 4 + 3] * inv[h])};
    *(f16x4*)&aggX[(size_t)dst * 1024 + h * 256 + lane * 4] = o;
  }
}

// ---------------- GEMM1 per head: A2 = elu(aggX_h @ W1_h^T + b1) -----------
// Writes EVERY row of A2[0..Mpad) (clamp affects only aggX reads) -> the old
// A2 pad-row memset is redundant and has been removed from the launcher.
__global__ __launch_bounds__(256) void gemm1_kernel(
    const f16* __restrict__ A, const f16* __restrict__ Bm,
    const float* __restrict__ bias, f16* __restrict__ C, int Nrows) {
  __shared__ f16 lA[128 * 32];
  __shared__ f16 lB[128 * 32];
  const int h = blockIdx.x;
  const int tid = threadIdx.x;
  const int w = tid >> 6, lane = tid & 63;
  const int wm = w >> 1, wn = w & 1;
  const int rowBase = blockIdx.y * 128;
  const int lrow = lane & 15, lk = lane >> 4;
  f32x4 acc[4][4];
#pragma unroll
  for (int i = 0; i < 4; ++i)
#pragma unroll
    for (int j = 0; j < 4; ++j) acc[i][j] = (f32x4){0.f, 0.f, 0.f, 0.f};

  for (int kv = 0; kv < 256; kv += 32) {
    f16x8 stA[2], stB[2];
#pragma unroll
    for (int s = 0; s < 2; ++s) {
      int q = s * 256 + tid;
      int r = q >> 2;
      int cs = (q & 3) ^ ((r >> 1) & 3);
      int row = rowBase + r;
      if (row >= Nrows) row = Nrows - 1;  // clamp: pad outputs unused
      stA[s] = *(const f16x8*)(A + (size_t)row * 1024 + h * 256 + kv + cs * 8);
    }
#pragma unroll
    for (int s = 0; s < 2; ++s) {
      int q = s * 256 + tid;
      int r = q >> 2;
      int cs = (q & 3) ^ ((r >> 1) & 3);
      stB[s] = *(const f16x8*)(Bm + (size_t)(h * 128 + r) * 256 + kv + cs * 8);
    }
#pragma unroll
    for (int s = 0; s < 2; ++s) *(f16x8*)&lA[(size_t)(s * 256 + tid) * 8] = stA[s];
#pragma unroll
    for (int s = 0; s < 2; ++s) *(f16x8*)&lB[(size_t)(s * 256 + tid) * 8] = stB[s];
    __syncthreads();
    f16x8 aF[4], bF[4];
#pragma unroll
    for (int i = 0; i < 4; ++i) {
      int ra = wm * 64 + i * 16 + lrow;
      aF[i] = *(const f16x8*)&lA[(ra * 4 + (lk ^ ((ra >> 1) & 3))) * 8];
      int rb = wn * 64 + i * 16 + lrow;
      bF[i] = *(const f16x8*)&lB[(rb * 4 + (lk ^ ((rb >> 1) & 3))) * 8];
    }
#pragma unroll
    for (int i = 0; i < 4; ++i)
#pragma unroll
      for (int j = 0; j < 4; ++j)
        acc[i][j] = __builtin_amdgcn_mfma_f32_16x16x32_f16(aF[i], bF[j], acc[i][j], 0, 0, 0);
    __syncthreads();
  }
  // epilogue: bias + ELU, store f16 (C/D layout: col=lane&15, row=(lane>>4)*4+reg)
  float bj[4];
#pragma unroll
  for (int j = 0; j < 4; ++j) bj[j] = bias[h * 128 + wn * 64 + j * 16 + lrow];
#pragma unroll
  for (int i = 0; i < 4; ++i) {
    int row0 = rowBase + wm * 64 + i * 16 + lk * 4;
#pragma unroll
    for (int j = 0; j < 4; ++j) {
      int col = h * 128 + wn * 64 + j * 16 + lrow;
#pragma unroll
      for (int rr = 0; rr < 4; ++rr) {
        float vv = acc[i][j][rr] + bj[j];
        vv = (vv > 0.f) ? vv : (__expf(vv) - 1.f);
        C[(size_t)(row0 + rr) * 512 + col] = (f16)vv;
      }
    }
  }
}

// ------------- GEMM2 (BM=64, TPB=256, wave-tile 32x64) + fused attn2 -------
__global__ __launch_bounds__(256) void gemm2_kernel(
    const f16* __restrict__ A, const f16* __restrict__ Bm, f16* __restrict__ C,
    const float* __restrict__ attS, const float* __restrict__ attD,
    float* __restrict__ aS, float* __restrict__ aD,
    int K, int Ncols, int Nrows) {
  __shared__ f16 lA[64 * 32];
  __shared__ f16 lB[128 * 32];
  const int tid = threadIdx.x;
  const int w = tid >> 6, lane = tid & 63;
  const int wm = w >> 1, wn = w & 1;
  const int rowBase = blockIdx.y * 64;
  const int lrow = lane & 15, lk = lane >> 4;
  f32x4 acc[2][4];
#pragma unroll
  for (int i = 0; i < 2; ++i)
#pragma unroll
    for (int j = 0; j < 4; ++j) acc[i][j] = (f32x4){0.f, 0.f, 0.f, 0.f};

  for (int kv = 0; kv < K; kv += 32) {
    f16x8 stA, stB[2];
    {
      int q = tid;
      int r = q >> 2;
      int cs = (q & 3) ^ ((r >> 1) & 3);
      stA = *(const f16x8*)(A + (size_t)(rowBase + r) * K + kv + cs * 8);
    }
#pragma unroll
    for (int s = 0; s < 2; ++s) {
      int q = s * 256 + tid;
      int r = q >> 2;
      int cs = (q & 3) ^ ((r >> 1) & 3);
      stB[s] = *(const f16x8*)(Bm + (size_t)r * K + kv + cs * 8);
    }
    *(f16x8*)&lA[(size_t)tid * 8] = stA;
#pragma unroll
    for (int s = 0; s < 2; ++s) *(f16x8*)&lB[(size_t)(s * 256 + tid) * 8] = stB[s];
    __syncthreads();
    f16x8 aF[2], bF[4];
#pragma unroll
    for (int i = 0; i < 2; ++i) {
      int ra = wm * 32 + i * 16 + lrow;
      aF[i] = *(const f16x8*)&lA[(ra * 4 + (lk ^ ((ra >> 1) & 3))) * 8];
    }
#pragma unroll
    for (int j = 0; j < 4; ++j) {
      int rb = wn * 64 + j * 16 + lrow;
      bF[j] = *(const f16x8*)&lB[(rb * 4 + (lk ^ ((rb >> 1) & 3))) * 8];
    }
#pragma unroll
    for (int i = 0; i < 2; ++i)
#pragma unroll
      for (int j = 0; j < 4; ++j)
        acc[i][j] = __builtin_amdgcn_mfma_f32_16x16x32_f16(aF[i], bF[j], acc[i][j], 0, 0, 0);
    __syncthreads();
  }
#pragma unroll
  for (int i = 0; i < 2; ++i) {
    int row0 = rowBase + wm * 32 + i * 16 + lk * 4;
#pragma unroll
    for (int j = 0; j < 4; ++j) {
      int col = wn * 64 + j * 16 + lrow;
#pragma unroll
      for (int rr = 0; rr < 4; ++rr)
        C[(size_t)(row0 + rr) * Ncols + col] = (f16)acc[i][j][rr];
    }
  }
  // Fused attn2 epilogue (H=1): rows split by wm, cols by wn.
  float sv[4], dv[4];
#pragma unroll
  for (int j = 0; j < 4; ++j) {
    int cl = wn * 64 + j * 16 + lrow;
    sv[j] = attS[cl];
    dv[j] = attD[cl];
  }
  __shared__ float sred[2][2][32][2];
#pragma unroll
  for (int i = 0; i < 2; ++i) {
#pragma unroll
    for (int rr = 0; rr < 4; ++rr) {
      float ps = 0.f, pd = 0.f;
#pragma unroll
      for (int j = 0; j < 4; ++j) {
        ps = fmaf(acc[i][j][rr], sv[j], ps);
        pd = fmaf(acc[i][j][rr], dv[j], pd);
      }
#pragma unroll
      for (int off = 1; off < 16; off <<= 1) {
        ps += __shfl_xor(ps, off);
        pd += __shfl_xor(pd, off);
      }
      if (lrow == 0) {
        int rloc = i * 16 + lk * 4 + rr;
        sred[wm][wn][rloc][0] = ps;
        sred[wm][wn][rloc][1] = pd;
      }
    }
  }
  __syncthreads();
  if (tid < 64) {
    int row = rowBase + tid;
    if (row < Nrows) {
      int m = tid >> 5, rl = tid & 31;
      aS[row] = sred[m][0][rl][0] + sred[m][1][rl][0];
      aD[row] = sred[m][0][rl][1] + sred[m][1][rl][1];
    }
  }
}

// ------------- layer-2 aggregation + ELU + fused classifier ----------------
__global__ __launch_bounds__(256) void agg2_kernel(
    const int* __restrict__ row_ptr, const int4* __restrict__ cse,
    const float* __restrict__ aS, const float* __restrict__ aD,
    const f16* __restrict__ xw2, const float* __restrict__ b2,
    const float* __restrict__ Wc, const float* __restrict__ bc,
    float* __restrict__ out, int n) {
  __shared__ __align__(16) float2 led[4][64];
  const int wv = threadIdx.x >> 6, lane = threadIdx.x & 63;
  const int dst = blockIdx.x * 4 + wv;
  if (dst >= n) return;
  const int beg = row_ptr[dst], end = row_ptr[dst + 1];
  const int half = lane >> 5, lc = lane & 31;
  const float ad = aD[dst];
  float den = 0.f;
  float acc[4] = {0.f, 0.f, 0.f, 0.f};
  const f16* __restrict__ xrow = xw2 + lc * 4;

  for (int base = beg; base < end; base += 64) {
    int i = base + lane;
    float2 pa = make_float2(__int_as_float(0), 0.f);
    if (i < end) {
      int s = cse[i].x;
      float x = aS[s] + ad;
      x = (x > 0.f) ? x : 0.2f * x;
      pa = make_float2(__int_as_float(s), __expf(x));
    }
    den += pa.y;
    led[wv][lane] = pa;
    asm volatile("s_waitcnt lgkmcnt(0)" ::: "memory");
    const int m = min(64, end - base);
    const int np2 = (m + 1) >> 1;
    int p = 0;
    for (; p < (np2 & ~7); p += 8) {
      int sj[8];
      float aj[8];
      f16x4 v[8];
#pragma unroll
      for (int k = 0; k < 8; ++k) {
        float2 q = led[wv][(p + k) * 2 + half];
        sj[k] = __float_as_int(q.x);
        aj[k] = q.y;
      }
#pragma unroll
      for (int k = 0; k < 8; ++k) v[k] = *(const f16x4*)&xrow[(size_t)sj[k] * 128];
#pragma unroll
      for (int k = 0; k < 8; ++k) {
        acc[0] = fmaf(aj[k], (float)v[k][0], acc[0]);
        acc[1] = fmaf(aj[k], (float)v[k][1], acc[1]);
        acc[2] = fmaf(aj[k], (float)v[k][2], acc[2]);
        acc[3] = fmaf(aj[k], (float)v[k][3], acc[3]);
      }
    }
    for (; p < np2; ++p) {
      const float2 q = led[wv][p * 2 + half];
      const int s = __float_as_int(q.x);
      const float a = q.y;
      const f16x4 vv = *(const f16x4*)&xrow[(size_t)s * 128];
      acc[0] = fmaf(a, (float)vv[0], acc[0]);
      acc[1] = fmaf(a, (float)vv[1], acc[1]);
      acc[2] = fmaf(a, (float)vv[2], acc[2]);
      acc[3] = fmaf(a, (float)vv[3], acc[3]);
    }
  }
#pragma unroll
  for (int off = 32; off; off >>= 1) den += __shfl_xor(den, off);
  const float inv = 1.f / den;
#pragma unroll
  for (int k = 0; k < 4; ++k) acc[k] += __shfl_xor(acc[k], 32);
  const int c = lc * 4;
  const float4 bb = *(const float4*)&b2[c];
  const float4 w0 = *(const float4*)&Wc[c];
  const float4 w1 = *(const float4*)&Wc[128 + c];
  const float bv[4] = {bb.x, bb.y, bb.z, bb.w};
  const float w0v[4] = {w0.x, w0.y, w0.z, w0.w};
  const float w1v[4] = {w1.x, w1.y, w1.z, w1.w};
  float l0 = 0.f, l1 = 0.f;
#pragma unroll
  for (int k = 0; k < 4; ++k) {
    float vv = acc[k] * inv + bv[k];
    vv = (vv > 0.f) ? vv : (__expf(vv) - 1.f);
    l0 = fmaf(vv, w0v[k], l0);
    l1 = fmaf(vv, w1v[k], l1);
  }
#pragma unroll
  for (int off = 16; off; off >>= 1) {
    l0 += __shfl_xor(l0, off);
    l1 += __shfl_xor(l1, off);
  }
  if (lane == 0) {
    out[dst * 2] = l0 + bc[0];
    out[dst * 2 + 1] = l1 + bc[1];
  }
}

// ---------------------------------------------------------------------------

extern "C" void kernel_launch(void* const* d_in, const int* in_sizes, int n_in,
                              void* d_out, int out_size, void* d_ws, size_t ws_size,
                              hipStream_t stream) {
  const float* x     = (const float*)d_in[0];
  const int*   ei    = (const int*)d_in[1];
  const float* W1    = (const float*)d_in[2];
  const float* att1s = (const float*)d_in[3];
  const float* att1d = (const float*)d_in[4];
  const float* b1    = (const float*)d_in[5];
  const float* W2    = (const float*)d_in[6];
  const float* att2s = (const float*)d_in[7];
  const float* att2d = (const float*)d_in[8];
  const float* b2    = (const float*)d_in[9];
  const float* Wc    = (const float*)d_in[10];
  const float* bc    = (const float*)d_in[11];
  float* out = (float*)d_out;

  const int N = in_sizes[0] / 256;
  const int E = in_sizes[1] / 2;
  const int EA = E + N;
  const int Mpad = (N + 127) & ~127;
  const int NB = (N + 255) / 256;
  const int EB = (EA + 255) / 256;
  const int CB = (N + 15) / 16;

  char* base = (char*)d_ws;
  size_t off = 0;
  auto alloc = [&](size_t bytes) -> char* {
    char* p = base + off;
    off = (off + bytes + 255) & ~(size_t)255;
    return p;
  };
  f16* aggX = (f16*)alloc((size_t)Mpad * 1024 * sizeof(f16));  // x-space agg (4 heads)
  f16* xf   = (f16*)alloc((size_t)Mpad * 256 * sizeof(f16));   // x in f16
  f16* B1f  = (f16*)alloc((size_t)512 * 256 * sizeof(f16));    // W1 f16
  f16* A2   = (f16*)alloc((size_t)Mpad * 512 * sizeof(f16));   // h = elu(layer1)
  f16* B2f  = (f16*)alloc((size_t)128 * 512 * sizeof(f16));    // W2 f16
  f16* xw2h = (f16*)alloc((size_t)Mpad * 128 * sizeof(f16));   // layer2 pre-agg
  float* attWT = (float*)alloc((size_t)8 * 256 * sizeof(float));
  float* aS1 = (float*)alloc((size_t)N * 4 * sizeof(float));
  float* aD1 = (float*)alloc((size_t)N * 4 * sizeof(float));
  float* aS2 = (float*)alloc((size_t)N * sizeof(float));
  float* aD2 = (float*)alloc((size_t)N * sizeof(float));
  int* deg     = (int*)alloc((size_t)N * sizeof(int));
  int* row_ptr = (int*)alloc((size_t)(N + 1) * sizeof(int));
  int* cursor  = (int*)alloc((size_t)N * sizeof(int));
  int4* cse    = (int4*)alloc((size_t)EA * sizeof(int4));  // {src,0,alpha4 f16x4}
  int* tmp     = (int*)alloc((size_t)N * sizeof(int));
  int* bsum    = (int*)alloc((size_t)NB * sizeof(int));
  (void)n_in; (void)out_size; (void)ws_size;

  hipMemsetAsync(deg, 0, (size_t)N * sizeof(int), stream);
  // (A2 pad memset removed: gemm1 writes all Mpad rows; pad values finite
  //  and never propagate -- cse[].x < N, aS2/aD2 writes guarded.)

  // prep1: attw (4) | cvtw (192) | hist (EB)   -- attw latency hidden
  prep1_kernel<<<196 + EB, 256, 0, stream>>>(W1, att1s, att1d, attWT,
                                             B1f, W2, B2f, ei, E, N, deg);
  // prep2: cvtx (CB) | scan1 (NB)
  prep2_kernel<<<CB + NB, 256, 0, stream>>>(x, attWT, xf, aS1, aD1, N, CB,
                                            deg, tmp, bsum);
  scan3_kernel<<<NB, 256, 0, stream>>>(deg, tmp, bsum, row_ptr, cursor, N, NB);
  scatter_kernel<<<EB, 256, 0, stream>>>(ei, E, N, aS1, aD1, cursor, cse);

  agg1_kernel<<<(N + 3) / 4, 256, 0, stream>>>(row_ptr, cse, xf, aggX, N);

  dim3 g1(4, Mpad / 128);
  gemm1_kernel<<<g1, 256, 0, stream>>>(aggX, B1f, b1, A2, N);

  dim3 g2(1, Mpad / 64);
  gemm2_kernel<<<g2, 256, 0, stream>>>(A2, B2f, xw2h, att2s, att2d, aS2, aD2, 512, 128, N);

  agg2_kernel<<<(N + 3) / 4, 256, 0, stream>>>(row_ptr, cse, aS2, aD2, xw2h, b2, Wc, bc, out, N);
}